// Round 2
// baseline (5989.338 us; speedup 1.0000x reference)
//
#include <hip/hip_runtime.h>
#include <hip/hip_bf16.h>
#include <math.h>

#define S_LEN 4096
#define HID 768
#define NHEAD 12
#define HDIM 64
#define NLAYER 2
#define WIN 256
#define FF 3072
#define N_ICD 8000
#define N_CPT 5000
#define N_CH 22

// ---------------- block reduce (deterministic) ----------------
__device__ __forceinline__ float breduce(float v, volatile float* red) {
    int t = threadIdx.x;
    #pragma unroll
    for (int o = 32; o > 0; o >>= 1) v += __shfl_down(v, o, 64);
    __syncthreads();
    if ((t & 63) == 0) red[t >> 6] = v;
    __syncthreads();
    float r = red[0] + red[1] + red[2] + red[3];
    return r;
}

// ---------------- embedding + LN ----------------
__global__ __launch_bounds__(256) void embed_ln_kernel(
    const int* __restrict__ ids, const float* __restrict__ we,
    const float* __restrict__ pe, const float* __restrict__ ls,
    const float* __restrict__ lb, float* __restrict__ x) {
    __shared__ float red[4];
    int srow = blockIdx.x, t = threadIdx.x;
    int id = ids[srow];
    float v[3];
    #pragma unroll
    for (int i = 0; i < 3; i++) {
        int hh = i * 256 + t;
        v[i] = we[(size_t)id * HID + hh] + pe[srow * HID + hh];
    }
    float s = v[0] + v[1] + v[2];
    float mean = breduce(s, red) * (1.f / HID);
    __syncthreads();
    float sq = 0.f;
    #pragma unroll
    for (int i = 0; i < 3; i++) { float d = v[i] - mean; sq += d * d; }
    float var = breduce(sq, red) * (1.f / HID);
    float inv = rsqrtf(var + 1e-5f);
    #pragma unroll
    for (int i = 0; i < 3; i++) {
        int hh = i * 256 + t;
        x[srow * HID + hh] = (v[i] - mean) * inv * ls[hh] + lb[hh];
    }
}

// ---------------- residual + LN (in-place on x) ----------------
__global__ __launch_bounds__(256) void residual_ln_kernel(
    float* __restrict__ x, const float* __restrict__ y,
    const float* __restrict__ ls, const float* __restrict__ lb) {
    __shared__ float red[4];
    int srow = blockIdx.x, t = threadIdx.x;
    float v[3];
    #pragma unroll
    for (int i = 0; i < 3; i++) {
        int hh = i * 256 + t;
        v[i] = x[srow * HID + hh] + y[srow * HID + hh];
    }
    float s = v[0] + v[1] + v[2];
    float mean = breduce(s, red) * (1.f / HID);
    __syncthreads();
    float sq = 0.f;
    #pragma unroll
    for (int i = 0; i < 3; i++) { float d = v[i] - mean; sq += d * d; }
    float var = breduce(sq, red) * (1.f / HID);
    float inv = rsqrtf(var + 1e-5f);
    #pragma unroll
    for (int i = 0; i < 3; i++) {
        int hh = i * 256 + t;
        x[srow * HID + hh] = (v[i] - mean) * inv * ls[hh] + lb[hh];
    }
}

// ---------------- generic fp32 GEMM: C = A(MxK) @ B(KxN) + bias, opt GELU ----------------
template<int ACT>
__global__ __launch_bounds__(256) void gemm_bias_kernel(
    const float* __restrict__ A, const float* __restrict__ Bw,
    const float* __restrict__ bias, float* __restrict__ C,
    int M, int N, int K) {
    __shared__ float As[16][65];
    __shared__ float Bs[16][65];
    int bn = blockIdx.x, bm = blockIdx.y;
    int t = threadIdx.x;
    int tx = t & 15, ty = t >> 4;
    int m0 = bm * 64, n0 = bn * 64;
    float acc[4][4] = {};
    for (int k0 = 0; k0 < K; k0 += 16) {
        {
            int k = t & 15, m = t >> 4;
            #pragma unroll
            for (int i = 0; i < 4; i++) {
                int mm = m + i * 16;
                As[k][mm] = A[(size_t)(m0 + mm) * K + k0 + k];
            }
        }
        {
            int n = t & 63, k = t >> 6;
            #pragma unroll
            for (int i = 0; i < 4; i++) {
                int kk = k + i * 4;
                Bs[kk][n] = Bw[(size_t)(k0 + kk) * N + n0 + n];
            }
        }
        __syncthreads();
        #pragma unroll
        for (int k = 0; k < 16; k++) {
            float a[4], b[4];
            #pragma unroll
            for (int i = 0; i < 4; i++) a[i] = As[k][ty * 4 + i];
            #pragma unroll
            for (int j = 0; j < 4; j++) b[j] = Bs[k][tx * 4 + j];
            #pragma unroll
            for (int i = 0; i < 4; i++)
                #pragma unroll
                for (int j = 0; j < 4; j++) acc[i][j] += a[i] * b[j];
        }
        __syncthreads();
    }
    #pragma unroll
    for (int i = 0; i < 4; i++) {
        int row = m0 + ty * 4 + i;
        #pragma unroll
        for (int j = 0; j < 4; j++) {
            int col = n0 + tx * 4 + j;
            float val = acc[i][j] + bias[col];
            if (ACT == 1) {
                float x3 = val * val * val;
                val = 0.5f * val * (1.f + tanhf(0.7978845608028654f * (val + 0.044715f * x3)));
            }
            C[(size_t)row * N + col] = val;
        }
    }
}

// ---------------- band (sliding window) attention, flash-style ----------------
// grid (S/64, H), block 512. QB=64 queries/block; strip of 9 x 64 keys.
// Thread (r=t>>3, sub=t&7): row r, keys sub+8j of each tile, output dims sub*8..sub*8+7.
#define QB 64
#define NT 9
__global__ __launch_bounds__(512) void band_attn_kernel(
    const float* __restrict__ q, const float* __restrict__ k,
    const float* __restrict__ v, const float* __restrict__ mask,
    float* __restrict__ ctx) {
    __shared__ float Qs[QB][68];
    __shared__ float Ks[64][68];
    __shared__ float Vs[64][68];
    __shared__ float Ms[NT * 64];

    int qblk = blockIdx.x, h = blockIdx.y;
    int qbase = qblk * QB;
    int kbase = qbase - WIN;
    int t = threadIdx.x;
    int r = t >> 3, sub = t & 7;
    int qp = qbase + r;

    // load Q tile: thread t -> row t>>3, col quads (t&7)*4 and (t&7)*4+32
    {
        int rr = t >> 3, c0 = (t & 7) * 4;
        const float* src = q + (size_t)(qbase + rr) * HID + h * 64;
        *(float4*)&Qs[rr][c0]      = *(const float4*)(src + c0);
        *(float4*)&Qs[rr][c0 + 32] = *(const float4*)(src + c0 + 32);
    }
    // mask strip (1 = attendable, 0 = masked/out-of-range)
    for (int i = t; i < NT * 64; i += 512) {
        int kp = kbase + i;
        float ok = 0.f;
        if (kp >= 0 && kp < S_LEN) ok = (mask[kp] > 0.5f) ? 1.f : 0.f;
        Ms[i] = ok;
    }

    float mrun = -1e9f;
    float lsum = 0.f;
    float acc[8] = {};
    const float scale = 0.125f;

    for (int kt = 0; kt < NT; kt++) {
        __syncthreads();
        // stage K and V tiles
        {
            int rr = t >> 3, c0 = (t & 7) * 4;
            int kp = kbase + kt * 64 + rr;
            if (kp >= 0 && kp < S_LEN) {
                const float* ks = k + (size_t)kp * HID + h * 64;
                const float* vs = v + (size_t)kp * HID + h * 64;
                *(float4*)&Ks[rr][c0]      = *(const float4*)(ks + c0);
                *(float4*)&Ks[rr][c0 + 32] = *(const float4*)(ks + c0 + 32);
                *(float4*)&Vs[rr][c0]      = *(const float4*)(vs + c0);
                *(float4*)&Vs[rr][c0 + 32] = *(const float4*)(vs + c0 + 32);
            } else {
                float4 z = make_float4(0.f, 0.f, 0.f, 0.f);
                *(float4*)&Ks[rr][c0] = z; *(float4*)&Ks[rr][c0 + 32] = z;
                *(float4*)&Vs[rr][c0] = z; *(float4*)&Vs[rr][c0 + 32] = z;
            }
        }
        __syncthreads();

        // scores for keys kk = sub + 8j
        float sc[8];
        #pragma unroll
        for (int j = 0; j < 8; j++) sc[j] = 0.f;
        #pragma unroll
        for (int dq = 0; dq < 16; dq++) {
            float4 q4 = *(const float4*)&Qs[r][dq * 4];
            #pragma unroll
            for (int j = 0; j < 8; j++) {
                float4 k4 = *(const float4*)&Ks[sub + 8 * j][dq * 4];
                sc[j] += q4.x * k4.x + q4.y * k4.y + q4.z * k4.z + q4.w * k4.w;
            }
        }
        float tm = -1e9f;
        #pragma unroll
        for (int j = 0; j < 8; j++) {
            int krel = kt * 64 + sub + 8 * j;
            int kp = kbase + krel;
            int d = kp - qp;
            bool ok = (d >= -WIN) && (d <= WIN) && (Ms[krel] != 0.f);
            sc[j] = ok ? sc[j] * scale : -1e9f;
            tm = fmaxf(tm, sc[j]);
        }
        #pragma unroll
        for (int o = 1; o < 8; o <<= 1) tm = fmaxf(tm, __shfl_xor(tm, o, 8));

        float newm = fmaxf(mrun, tm);
        float corr = __expf(mrun - newm);
        lsum *= corr;
        #pragma unroll
        for (int jj = 0; jj < 8; jj++) acc[jj] *= corr;
        float p[8];
        #pragma unroll
        for (int j = 0; j < 8; j++) {
            p[j] = __expf(sc[j] - newm);
            lsum += p[j];
        }
        mrun = newm;

        // PV: broadcast p across the row's 8 lanes
        #pragma unroll
        for (int kk = 0; kk < 64; kk++) {
            float pk = __shfl(p[kk >> 3], kk & 7, 8);
            float4 v4a = *(const float4*)&Vs[kk][sub * 8];
            float4 v4b = *(const float4*)&Vs[kk][sub * 8 + 4];
            acc[0] += pk * v4a.x; acc[1] += pk * v4a.y;
            acc[2] += pk * v4a.z; acc[3] += pk * v4a.w;
            acc[4] += pk * v4b.x; acc[5] += pk * v4b.y;
            acc[6] += pk * v4b.z; acc[7] += pk * v4b.w;
        }
    }

    #pragma unroll
    for (int o = 1; o < 8; o <<= 1) lsum += __shfl_xor(lsum, o, 8);
    float inv = 1.f / lsum;
    float* dst = ctx + (size_t)qp * HID + h * 64 + sub * 8;
    float4 o1 = make_float4(acc[0] * inv, acc[1] * inv, acc[2] * inv, acc[3] * inv);
    float4 o2 = make_float4(acc[4] * inv, acc[5] * inv, acc[6] * inv, acc[7] * inv);
    *(float4*)dst = o1;
    *(float4*)(dst + 4) = o2;
}

// ---------------- classifier head ----------------
__global__ __launch_bounds__(256) void head_logits_kernel(
    const float* __restrict__ x0, const float* __restrict__ Wt,
    const float* __restrict__ bias, float* __restrict__ out, int N) {
    __shared__ float p[HID];
    int t = threadIdx.x;
    for (int i = t; i < HID; i += 256) p[i] = x0[i];
    __syncthreads();
    int n = blockIdx.x * 256 + t;
    if (n < N) {
        float acc = bias[n];
        for (int hh = 0; hh < HID; hh++) acc += p[hh] * Wt[(size_t)hh * N + n];
        out[n] = acc;
    }
}

// ---------------- focal loss partials (deterministic tree) ----------------
__global__ __launch_bounds__(256) void focal_partial_kernel(
    const float* __restrict__ logits, const float* __restrict__ tgt,
    int N, float* __restrict__ partials) {
    __shared__ float red[256];
    int t = threadIdx.x;
    float s = 0.f;
    for (int i = blockIdx.x * 256 + t; i < N; i += gridDim.x * 256) {
        float l = logits[i], y = tgt[i];
        float bce = fmaxf(l, 0.f) - l * y + log1pf(expf(-fabsf(l)));
        float pt = expf(-bce);
        float om = 1.f - pt;
        s += om * om * bce;
    }
    red[t] = s;
    __syncthreads();
    for (int o = 128; o > 0; o >>= 1) {
        if (t < o) red[t] += red[t + o];
        __syncthreads();
    }
    if (t == 0) partials[blockIdx.x] = red[0];
}

__global__ void final_loss_kernel(const float* __restrict__ parts, float* __restrict__ out) {
    if (threadIdx.x == 0 && blockIdx.x == 0) {
        float a = 0.f, b = 0.f, c = 0.f;
        for (int i = 0; i < 32; i++) a += parts[i];
        for (int i = 0; i < 32; i++) b += parts[32 + i];
        for (int i = 0; i < 32; i++) c += parts[64 + i];
        out[0] = a / (float)N_ICD + b / (float)N_CPT + c / (float)N_CH;
    }
}

// ---------------- launch ----------------
extern "C" void kernel_launch(void* const* d_in, const int* in_sizes, int n_in,
                              void* d_out, int out_size, void* d_ws, size_t ws_size,
                              hipStream_t stream) {
    const int*   ids      = (const int*)d_in[0];
    const float* mask     = (const float*)d_in[1];
    const float* icd_lab  = (const float*)d_in[2];
    const float* cpt_lab  = (const float*)d_in[3];
    const float* ch_lab   = (const float*)d_in[4];
    const float* we       = (const float*)d_in[5];
    const float* pe       = (const float*)d_in[6];
    const float* els      = (const float*)d_in[7];
    const float* elb      = (const float*)d_in[8];
    const float* Wq       = (const float*)d_in[9];
    const float* bq       = (const float*)d_in[10];
    const float* Wk       = (const float*)d_in[11];
    const float* bk       = (const float*)d_in[12];
    const float* Wv       = (const float*)d_in[13];
    const float* bv       = (const float*)d_in[14];
    const float* Wo       = (const float*)d_in[15];
    const float* bo       = (const float*)d_in[16];
    const float* l1s      = (const float*)d_in[17];
    const float* l1b      = (const float*)d_in[18];
    const float* Wi       = (const float*)d_in[19];
    const float* bi       = (const float*)d_in[20];
    const float* Wo2      = (const float*)d_in[21];
    const float* bo2      = (const float*)d_in[22];
    const float* l2s      = (const float*)d_in[23];
    const float* l2b      = (const float*)d_in[24];
    const float* W_icd    = (const float*)d_in[25];
    const float* b_icd    = (const float*)d_in[26];
    const float* W_cpt    = (const float*)d_in[27];
    const float* b_cpt    = (const float*)d_in[28];
    const float* W_ch     = (const float*)d_in[29];
    const float* b_ch     = (const float*)d_in[30];

    const size_t SH = (size_t)S_LEN * HID;
    float* ws   = (float*)d_ws;
    float* x    = ws;
    float* qb   = x + SH;
    float* kb   = qb + SH;
    float* vb   = kb + SH;
    float* ctx  = vb + SH;
    float* tmp  = ctx + SH;
    float* ffh  = tmp + SH;
    float* chl  = ffh + (size_t)S_LEN * FF;
    float* parts = chl + 32;

    float* out = (float*)d_out;
    float* icd_logits = out + 1;
    float* cpt_logits = out + 1 + N_ICD;

    embed_ln_kernel<<<S_LEN, 256, 0, stream>>>(ids, we, pe, els, elb, x);

    for (int l = 0; l < NLAYER; l++) {
        const float* wq = Wq + (size_t)l * HID * HID;
        const float* wk = Wk + (size_t)l * HID * HID;
        const float* wv = Wv + (size_t)l * HID * HID;
        const float* wo = Wo + (size_t)l * HID * HID;
        const float* wi = Wi + (size_t)l * HID * FF;
        const float* wo2 = Wo2 + (size_t)l * FF * HID;

        dim3 g1(HID / 64, S_LEN / 64);
        gemm_bias_kernel<0><<<g1, 256, 0, stream>>>(x, wq, bq + l * HID, qb, S_LEN, HID, HID);
        gemm_bias_kernel<0><<<g1, 256, 0, stream>>>(x, wk, bk + l * HID, kb, S_LEN, HID, HID);
        gemm_bias_kernel<0><<<g1, 256, 0, stream>>>(x, wv, bv + l * HID, vb, S_LEN, HID, HID);

        band_attn_kernel<<<dim3(S_LEN / QB, NHEAD), 512, 0, stream>>>(qb, kb, vb, mask, ctx);

        gemm_bias_kernel<0><<<g1, 256, 0, stream>>>(ctx, wo, bo + l * HID, tmp, S_LEN, HID, HID);
        residual_ln_kernel<<<S_LEN, 256, 0, stream>>>(x, tmp, l1s + l * HID, l1b + l * HID);

        gemm_bias_kernel<1><<<dim3(FF / 64, S_LEN / 64), 256, 0, stream>>>(x, wi, bi + l * FF, ffh, S_LEN, FF, HID);
        gemm_bias_kernel<0><<<g1, 256, 0, stream>>>(ffh, wo2, bo2 + l * HID, tmp, S_LEN, HID, FF);
        residual_ln_kernel<<<S_LEN, 256, 0, stream>>>(x, tmp, l2s + l * HID, l2b + l * HID);
    }

    head_logits_kernel<<<(N_ICD + 255) / 256, 256, 0, stream>>>(x, W_icd, b_icd, icd_logits, N_ICD);
    head_logits_kernel<<<(N_CPT + 255) / 256, 256, 0, stream>>>(x, W_cpt, b_cpt, cpt_logits, N_CPT);
    head_logits_kernel<<<1, 256, 0, stream>>>(x, W_ch, b_ch, chl, N_CH);

    focal_partial_kernel<<<32, 256, 0, stream>>>(icd_logits, icd_lab, N_ICD, parts);
    focal_partial_kernel<<<32, 256, 0, stream>>>(cpt_logits, cpt_lab, N_CPT, parts + 32);
    focal_partial_kernel<<<32, 256, 0, stream>>>(chl, ch_lab, N_CH, parts + 64);
    final_loss_kernel<<<1, 1, 0, stream>>>(parts, out);
}

// Round 3
// 2154.517 us; speedup vs baseline: 2.7799x; 2.7799x over previous
//
#include <hip/hip_runtime.h>
#include <hip/hip_bf16.h>
#include <math.h>

#define S_LEN 4096
#define HID 768
#define NHEAD 12
#define NLAYER 2
#define WIN 256
#define FF 3072
#define N_ICD 8000
#define N_CPT 5000
#define N_CH 22

typedef short s16x8 __attribute__((ext_vector_type(8)));
typedef float fx4 __attribute__((ext_vector_type(4)));

__device__ __forceinline__ ushort f2bf(float f) {
    union { float f; uint u; } c; c.f = f;
    uint u = c.u + 0x7fffu + ((c.u >> 16) & 1u);
    return (ushort)(u >> 16);
}

// ---------------- block reduce (deterministic) ----------------
__device__ __forceinline__ float breduce(float v, volatile float* red) {
    int t = threadIdx.x;
    #pragma unroll
    for (int o = 32; o > 0; o >>= 1) v += __shfl_down(v, o, 64);
    __syncthreads();
    if ((t & 63) == 0) red[t >> 6] = v;
    __syncthreads();
    return red[0] + red[1] + red[2] + red[3];
}

// ---------------- weight transpose + bf16 convert: in[K][N] f32 -> out[N][K] bf16 ----------------
__global__ __launch_bounds__(256) void trans_kernel(
    const float* __restrict__ in, ushort* __restrict__ out,
    int K, int N, size_t in_z, size_t out_z) {
    __shared__ float T[32][33];
    in += blockIdx.z * in_z; out += blockIdx.z * out_z;
    int tx = threadIdx.x & 31, ty = threadIdx.x >> 5;
    int n0 = blockIdx.x * 32, k0 = blockIdx.y * 32;
    #pragma unroll
    for (int i = 0; i < 32; i += 8)
        T[ty + i][tx] = in[(size_t)(k0 + ty + i) * N + n0 + tx];
    __syncthreads();
    #pragma unroll
    for (int i = 0; i < 32; i += 8)
        out[(size_t)(n0 + ty + i) * K + k0 + tx] = f2bf(T[tx][ty + i]);
}

// ---------------- pack QKV bias ----------------
__global__ __launch_bounds__(256) void pack_bias_kernel(
    const float* __restrict__ bq, const float* __restrict__ bk,
    const float* __restrict__ bv, float* __restrict__ dst) {
    int i = blockIdx.x * 256 + threadIdx.x;
    if (i < HID) { dst[i] = bq[i]; dst[HID + i] = bk[i]; dst[2 * HID + i] = bv[i]; }
}

// ---------------- embedding + LN (writes f32 x and bf16 xb) ----------------
__global__ __launch_bounds__(256) void embed_ln_kernel(
    const int* __restrict__ ids, const float* __restrict__ we,
    const float* __restrict__ pe, const float* __restrict__ ls,
    const float* __restrict__ lb, float* __restrict__ x, ushort* __restrict__ xb) {
    __shared__ float red[4];
    int srow = blockIdx.x, t = threadIdx.x;
    int id = ids[srow];
    float v[3];
    #pragma unroll
    for (int i = 0; i < 3; i++) {
        int hh = i * 256 + t;
        v[i] = we[(size_t)id * HID + hh] + pe[srow * HID + hh];
    }
    float mean = breduce(v[0] + v[1] + v[2], red) * (1.f / HID);
    __syncthreads();
    float sq = 0.f;
    #pragma unroll
    for (int i = 0; i < 3; i++) { float d = v[i] - mean; sq += d * d; }
    float var = breduce(sq, red) * (1.f / HID);
    float inv = rsqrtf(var + 1e-5f);
    #pragma unroll
    for (int i = 0; i < 3; i++) {
        int hh = i * 256 + t;
        float o = (v[i] - mean) * inv * ls[hh] + lb[hh];
        x[srow * HID + hh] = o;
        xb[srow * HID + hh] = f2bf(o);
    }
}

// ---------------- residual + LN (in-place on x, also writes bf16 xb) ----------------
__global__ __launch_bounds__(256) void residual_ln_kernel(
    float* __restrict__ x, const float* __restrict__ y,
    const float* __restrict__ ls, const float* __restrict__ lb,
    ushort* __restrict__ xb) {
    __shared__ float red[4];
    int srow = blockIdx.x, t = threadIdx.x;
    float v[3];
    #pragma unroll
    for (int i = 0; i < 3; i++) {
        int hh = i * 256 + t;
        v[i] = x[srow * HID + hh] + y[srow * HID + hh];
    }
    float mean = breduce(v[0] + v[1] + v[2], red) * (1.f / HID);
    __syncthreads();
    float sq = 0.f;
    #pragma unroll
    for (int i = 0; i < 3; i++) { float d = v[i] - mean; sq += d * d; }
    float var = breduce(sq, red) * (1.f / HID);
    float inv = rsqrtf(var + 1e-5f);
    #pragma unroll
    for (int i = 0; i < 3; i++) {
        int hh = i * 256 + t;
        float o = (v[i] - mean) * inv * ls[hh] + lb[hh];
        x[srow * HID + hh] = o;
        xb[srow * HID + hh] = f2bf(o);
    }
}

// ---------------- bf16 MFMA GEMM: C = A(MxK,bf16) @ Bt(NxK,bf16)^T + bias ----------------
// 128x128 tile, 4 waves (2x2), each wave 64x64 via 4x4 frags of 16x16x32.
template<int ACT, int OUTF32, int OUTBF16>
__global__ __launch_bounds__(256) void gemm_mfma_kernel(
    const ushort* __restrict__ A, const ushort* __restrict__ Bt,
    const float* __restrict__ bias, float* __restrict__ C,
    ushort* __restrict__ Cb, int M, int N, int K) {
    __shared__ ushort As[128][40];   // pad 32->40 (80B rows, 16B aligned)
    __shared__ ushort Bs[128][40];
    int t = threadIdx.x;
    int lane = t & 63, wid = t >> 6;
    int m0 = blockIdx.y * 128, n0 = blockIdx.x * 128;
    int wr = (wid >> 1) * 64, wc = (wid & 1) * 64;
    fx4 acc[4][4];
    #pragma unroll
    for (int i = 0; i < 4; i++)
        #pragma unroll
        for (int j = 0; j < 4; j++) acc[i][j] = (fx4){0.f, 0.f, 0.f, 0.f};

    int rr = t >> 2, koff = (t & 3) * 8;
    const ushort* pa0 = A + (size_t)(m0 + rr) * K + koff;
    const ushort* pa1 = A + (size_t)(m0 + rr + 64) * K + koff;
    const ushort* pb0 = Bt + (size_t)(n0 + rr) * K + koff;
    const ushort* pb1 = Bt + (size_t)(n0 + rr + 64) * K + koff;

    for (int k0 = 0; k0 < K; k0 += 32) {
        *(uint4*)&As[rr][koff]      = *(const uint4*)(pa0 + k0);
        *(uint4*)&As[rr + 64][koff] = *(const uint4*)(pa1 + k0);
        *(uint4*)&Bs[rr][koff]      = *(const uint4*)(pb0 + k0);
        *(uint4*)&Bs[rr + 64][koff] = *(const uint4*)(pb1 + k0);
        __syncthreads();
        s16x8 a[4], b[4];
        #pragma unroll
        for (int f = 0; f < 4; f++) {
            a[f] = *(const s16x8*)&As[wr + f * 16 + (lane & 15)][(lane >> 4) * 8];
            b[f] = *(const s16x8*)&Bs[wc + f * 16 + (lane & 15)][(lane >> 4) * 8];
        }
        #pragma unroll
        for (int i = 0; i < 4; i++)
            #pragma unroll
            for (int j = 0; j < 4; j++)
                acc[i][j] = __builtin_amdgcn_mfma_f32_16x16x32_bf16(a[i], b[j], acc[i][j], 0, 0, 0);
        __syncthreads();
    }
    int crow = (lane >> 4) * 4, ccol = lane & 15;
    #pragma unroll
    for (int i = 0; i < 4; i++) {
        #pragma unroll
        for (int j = 0; j < 4; j++) {
            int col = n0 + wc + j * 16 + ccol;
            float bv_ = bias[col];
            #pragma unroll
            for (int r = 0; r < 4; r++) {
                int row = m0 + wr + i * 16 + crow + r;
                float val = acc[i][j][r] + bv_;
                if (ACT) {
                    float tt = 0.7978845608028654f * (val + 0.044715f * val * val * val);
                    val = val * (1.f / (1.f + __expf(-2.f * tt)));   // val*sigmoid(2t) = gelu tanh
                }
                if (OUTF32) C[(size_t)row * N + col] = val;
                if (OUTBF16) Cb[(size_t)row * N + col] = f2bf(val);
            }
        }
    }
}

// ---------------- band attention, flash-style, QB=32, 256 threads ----------------
// qkv layout: [S][2304] f32 (q | k | v). Writes bf16 ctx [S][768].
#define QB 32
#define NT 9
__global__ __launch_bounds__(256) void band_attn_kernel(
    const float* __restrict__ qkv, const float* __restrict__ mask,
    ushort* __restrict__ ctxb) {
    __shared__ float Qs[QB][68];
    __shared__ float Ks[64][68];
    __shared__ float Vs[64][68];
    __shared__ float Ms[NT * 64];

    int qblk = blockIdx.x, h = blockIdx.y;
    int qbase = qblk * QB, kbase = qbase - WIN;
    int t = threadIdx.x;
    int r = t >> 3, sub = t & 7;
    int qp = qbase + r;
    const float* qP = qkv + h * 64;
    const float* kP = qkv + HID + h * 64;
    const float* vP = qkv + 2 * HID + h * 64;

    {
        int rq = t >> 3, c0 = (t & 7) * 8;
        const float* src = qP + (size_t)(qbase + rq) * 2304;
        *(float4*)&Qs[rq][c0]     = *(const float4*)(src + c0);
        *(float4*)&Qs[rq][c0 + 4] = *(const float4*)(src + c0 + 4);
    }
    for (int i = t; i < NT * 64; i += 256) {
        int kp = kbase + i;
        Ms[i] = (kp >= 0 && kp < S_LEN && mask[kp] > 0.5f) ? 1.f : 0.f;
    }

    float mrun = -1e30f, lsum = 0.f;
    float acc[8] = {};
    const float scale = 0.125f;

    for (int kt = 0; kt < NT; kt++) {
        __syncthreads();
        {
            int rk = t >> 2, c0 = (t & 3) * 16;
            int kp = kbase + kt * 64 + rk;
            if (kp >= 0 && kp < S_LEN) {
                const float* ks = kP + (size_t)kp * 2304;
                const float* vs = vP + (size_t)kp * 2304;
                #pragma unroll
                for (int c = 0; c < 16; c += 4) {
                    *(float4*)&Ks[rk][c0 + c] = *(const float4*)(ks + c0 + c);
                    *(float4*)&Vs[rk][c0 + c] = *(const float4*)(vs + c0 + c);
                }
            } else {
                float4 z = make_float4(0.f, 0.f, 0.f, 0.f);
                #pragma unroll
                for (int c = 0; c < 16; c += 4) {
                    *(float4*)&Ks[rk][c0 + c] = z;
                    *(float4*)&Vs[rk][c0 + c] = z;
                }
            }
        }
        __syncthreads();

        float sc[8];
        #pragma unroll
        for (int j = 0; j < 8; j++) sc[j] = 0.f;
        #pragma unroll
        for (int dq = 0; dq < 16; dq++) {
            float4 q4 = *(const float4*)&Qs[r][dq * 4];
            #pragma unroll
            for (int j = 0; j < 8; j++) {
                float4 k4 = *(const float4*)&Ks[sub + 8 * j][dq * 4];
                sc[j] += q4.x * k4.x + q4.y * k4.y + q4.z * k4.z + q4.w * k4.w;
            }
        }
        float tm = -1e30f;
        #pragma unroll
        for (int j = 0; j < 8; j++) {
            int krel = kt * 64 + sub + 8 * j;
            int d = kbase + krel - qp;
            bool ok = (d >= -WIN) && (d <= WIN) && (Ms[krel] != 0.f);
            sc[j] = ok ? sc[j] * scale : -1e30f;
            tm = fmaxf(tm, sc[j]);
        }
        #pragma unroll
        for (int o = 1; o < 8; o <<= 1) tm = fmaxf(tm, __shfl_xor(tm, o, 8));

        float newm = fmaxf(mrun, tm);
        float corr = __expf(mrun - newm);
        lsum *= corr;
        #pragma unroll
        for (int jj = 0; jj < 8; jj++) acc[jj] *= corr;
        float p[8];
        #pragma unroll
        for (int j = 0; j < 8; j++) {
            p[j] = __expf(sc[j] - newm);
            lsum += p[j];
        }
        mrun = newm;

        #pragma unroll
        for (int kk = 0; kk < 64; kk++) {
            float pk = __shfl(p[kk >> 3], kk & 7, 8);
            float4 v4a = *(const float4*)&Vs[kk][sub * 8];
            float4 v4b = *(const float4*)&Vs[kk][sub * 8 + 4];
            acc[0] += pk * v4a.x; acc[1] += pk * v4a.y;
            acc[2] += pk * v4a.z; acc[3] += pk * v4a.w;
            acc[4] += pk * v4b.x; acc[5] += pk * v4b.y;
            acc[6] += pk * v4b.z; acc[7] += pk * v4b.w;
        }
    }

    #pragma unroll
    for (int o = 1; o < 8; o <<= 1) lsum += __shfl_xor(lsum, o, 8);
    float inv = 1.f / lsum;
    ushort* dst = ctxb + (size_t)qp * HID + h * 64 + sub * 8;
    uint4 w;
    w.x = (uint)f2bf(acc[0] * inv) | ((uint)f2bf(acc[1] * inv) << 16);
    w.y = (uint)f2bf(acc[2] * inv) | ((uint)f2bf(acc[3] * inv) << 16);
    w.z = (uint)f2bf(acc[4] * inv) | ((uint)f2bf(acc[5] * inv) << 16);
    w.w = (uint)f2bf(acc[6] * inv) | ((uint)f2bf(acc[7] * inv) << 16);
    *(uint4*)dst = w;
}

// ---------------- classifier head ----------------
__global__ __launch_bounds__(256) void head_logits_kernel(
    const float* __restrict__ x0, const float* __restrict__ Wt,
    const float* __restrict__ bias, float* __restrict__ out, int N) {
    __shared__ float p[HID];
    int t = threadIdx.x;
    for (int i = t; i < HID; i += 256) p[i] = x0[i];
    __syncthreads();
    int n = blockIdx.x * 256 + t;
    if (n < N) {
        float acc = bias[n];
        for (int hh = 0; hh < HID; hh++) acc += p[hh] * Wt[(size_t)hh * N + n];
        out[n] = acc;
    }
}

// ---------------- focal loss ----------------
__global__ __launch_bounds__(256) void focal_partial_kernel(
    const float* __restrict__ logits, const float* __restrict__ tgt,
    int N, float* __restrict__ partials) {
    __shared__ float red[256];
    int t = threadIdx.x;
    float s = 0.f;
    for (int i = blockIdx.x * 256 + t; i < N; i += gridDim.x * 256) {
        float l = logits[i], y = tgt[i];
        float bce = fmaxf(l, 0.f) - l * y + log1pf(expf(-fabsf(l)));
        float pt = expf(-bce);
        float om = 1.f - pt;
        s += om * om * bce;
    }
    red[t] = s;
    __syncthreads();
    for (int o = 128; o > 0; o >>= 1) {
        if (t < o) red[t] += red[t + o];
        __syncthreads();
    }
    if (t == 0) partials[blockIdx.x] = red[0];
}

__global__ void final_loss_kernel(const float* __restrict__ parts, float* __restrict__ out) {
    if (threadIdx.x == 0 && blockIdx.x == 0) {
        float a = 0.f, b = 0.f, c = 0.f;
        for (int i = 0; i < 32; i++) a += parts[i];
        for (int i = 0; i < 32; i++) b += parts[32 + i];
        for (int i = 0; i < 32; i++) c += parts[64 + i];
        out[0] = a / (float)N_ICD + b / (float)N_CPT + c / (float)N_CH;
    }
}

// ---------------- launch ----------------
extern "C" void kernel_launch(void* const* d_in, const int* in_sizes, int n_in,
                              void* d_out, int out_size, void* d_ws, size_t ws_size,
                              hipStream_t stream) {
    const int*   ids      = (const int*)d_in[0];
    const float* mask     = (const float*)d_in[1];
    const float* icd_lab  = (const float*)d_in[2];
    const float* cpt_lab  = (const float*)d_in[3];
    const float* ch_lab   = (const float*)d_in[4];
    const float* we       = (const float*)d_in[5];
    const float* pe       = (const float*)d_in[6];
    const float* els      = (const float*)d_in[7];
    const float* elb      = (const float*)d_in[8];
    const float* Wq       = (const float*)d_in[9];
    const float* bq       = (const float*)d_in[10];
    const float* Wk       = (const float*)d_in[11];
    const float* bk       = (const float*)d_in[12];
    const float* Wv       = (const float*)d_in[13];
    const float* bv       = (const float*)d_in[14];
    const float* Wo       = (const float*)d_in[15];
    const float* bo       = (const float*)d_in[16];
    const float* l1s      = (const float*)d_in[17];
    const float* l1b      = (const float*)d_in[18];
    const float* Wi       = (const float*)d_in[19];
    const float* bi       = (const float*)d_in[20];
    const float* Wo2      = (const float*)d_in[21];
    const float* bo2      = (const float*)d_in[22];
    const float* l2s      = (const float*)d_in[23];
    const float* l2b      = (const float*)d_in[24];
    const float* W_icd    = (const float*)d_in[25];
    const float* b_icd    = (const float*)d_in[26];
    const float* W_cpt    = (const float*)d_in[27];
    const float* b_cpt    = (const float*)d_in[28];
    const float* W_ch     = (const float*)d_in[29];
    const float* b_ch     = (const float*)d_in[30];

    const size_t SH = (size_t)S_LEN * HID;
    const size_t WW = (size_t)HID * HID;        // 589824
    const size_t WI = (size_t)HID * FF;         // 2359296

    float* x     = (float*)d_ws;                // SH
    float* qkv   = x + SH;                      // S*2304
    float* tmp   = qkv + (size_t)S_LEN * 3 * HID; // SH
    float* bqkv  = tmp + SH;                    // 2304
    float* chl   = bqkv + 2304;                 // 32
    float* parts = chl + 32;                    // 96
    ushort* xb      = (ushort*)(parts + 96);    // SH
    ushort* ctxb    = xb + SH;                  // SH
    ushort* ffhb    = ctxb + SH;                // S*FF
    ushort* wt_qkvo = ffhb + (size_t)S_LEN * FF; // 8*WW  [layer][q,k,v,o][n][k]
    ushort* wt_i    = wt_qkvo + 8 * WW;         // 2*WI  [layer][n=3072][k=768]
    ushort* wt_o2   = wt_i + 2 * WI;            // 2*WI  [layer][n=768][k=3072]

    float* out = (float*)d_out;
    float* icd_logits = out + 1;
    float* cpt_logits = out + 1 + N_ICD;

    // ---- weight prep (runs every launch; deterministic) ----
    trans_kernel<<<dim3(HID/32, HID/32, 2), 256, 0, stream>>>(Wq,  wt_qkvo + 0*WW, HID, HID, WW, 4*WW);
    trans_kernel<<<dim3(HID/32, HID/32, 2), 256, 0, stream>>>(Wk,  wt_qkvo + 1*WW, HID, HID, WW, 4*WW);
    trans_kernel<<<dim3(HID/32, HID/32, 2), 256, 0, stream>>>(Wv,  wt_qkvo + 2*WW, HID, HID, WW, 4*WW);
    trans_kernel<<<dim3(HID/32, HID/32, 2), 256, 0, stream>>>(Wo,  wt_qkvo + 3*WW, HID, HID, WW, 4*WW);
    trans_kernel<<<dim3(FF/32,  HID/32, 2), 256, 0, stream>>>(Wi,  wt_i,  HID, FF, WI, WI);
    trans_kernel<<<dim3(HID/32, FF/32,  2), 256, 0, stream>>>(Wo2, wt_o2, FF, HID, WI, WI);

    embed_ln_kernel<<<S_LEN, 256, 0, stream>>>(ids, we, pe, els, elb, x, xb);

    for (int l = 0; l < NLAYER; l++) {
        const ushort* wt_qkv_l = wt_qkvo + (size_t)l * 4 * WW;
        const ushort* wt_o_l   = wt_qkvo + (size_t)l * 4 * WW + 3 * WW;
        const ushort* wt_i_l   = wt_i  + (size_t)l * WI;
        const ushort* wt_o2_l  = wt_o2 + (size_t)l * WI;

        pack_bias_kernel<<<3, 256, 0, stream>>>(bq + l*HID, bk + l*HID, bv + l*HID, bqkv);
        gemm_mfma_kernel<0,1,0><<<dim3(2304/128, S_LEN/128), 256, 0, stream>>>(
            xb, wt_qkv_l, bqkv, qkv, nullptr, S_LEN, 2304, HID);

        band_attn_kernel<<<dim3(S_LEN/QB, NHEAD), 256, 0, stream>>>(qkv, mask, ctxb);

        gemm_mfma_kernel<0,1,0><<<dim3(HID/128, S_LEN/128), 256, 0, stream>>>(
            ctxb, wt_o_l, bo + l*HID, tmp, nullptr, S_LEN, HID, HID);
        residual_ln_kernel<<<S_LEN, 256, 0, stream>>>(x, tmp, l1s + l*HID, l1b + l*HID, xb);

        gemm_mfma_kernel<1,0,1><<<dim3(FF/128, S_LEN/128), 256, 0, stream>>>(
            xb, wt_i_l, bi + l*FF, nullptr, ffhb, S_LEN, FF, HID);
        gemm_mfma_kernel<0,1,0><<<dim3(HID/128, S_LEN/128), 256, 0, stream>>>(
            ffhb, wt_o2_l, bo2 + l*HID, tmp, nullptr, S_LEN, HID, FF);
        residual_ln_kernel<<<S_LEN, 256, 0, stream>>>(x, tmp, l2s + l*HID, l2b + l*HID, xb);
    }

    head_logits_kernel<<<(N_ICD + 255) / 256, 256, 0, stream>>>(x, W_icd, b_icd, icd_logits, N_ICD);
    head_logits_kernel<<<(N_CPT + 255) / 256, 256, 0, stream>>>(x, W_cpt, b_cpt, cpt_logits, N_CPT);
    head_logits_kernel<<<1, 256, 0, stream>>>(x, W_ch, b_ch, chl, N_CH);

    focal_partial_kernel<<<32, 256, 0, stream>>>(icd_logits, icd_lab, N_ICD, parts);
    focal_partial_kernel<<<32, 256, 0, stream>>>(cpt_logits, cpt_lab, N_CPT, parts + 32);
    focal_partial_kernel<<<32, 256, 0, stream>>>(chl, ch_lab, N_CH, parts + 64);
    final_loss_kernel<<<1, 1, 0, stream>>>(parts, out);
}

// Round 4
// 653.824 us; speedup vs baseline: 9.1605x; 3.2953x over previous
//
#include <hip/hip_runtime.h>
#include <hip/hip_bf16.h>
#include <math.h>

#define S_LEN 4096
#define HID 768
#define NHEAD 12
#define NLAYER 2
#define WIN 256
#define FF 3072
#define N_ICD 8000
#define N_CPT 5000
#define N_CH 22

typedef short s16x8 __attribute__((ext_vector_type(8)));
typedef float fx4 __attribute__((ext_vector_type(4)));

__device__ __forceinline__ ushort f2bf(float f) {
    union { float f; uint u; } c; c.f = f;
    uint u = c.u + 0x7fffu + ((c.u >> 16) & 1u);
    return (ushort)(u >> 16);
}

// ---------------- block reduce (deterministic) ----------------
__device__ __forceinline__ float breduce(float v, volatile float* red) {
    int t = threadIdx.x;
    #pragma unroll
    for (int o = 32; o > 0; o >>= 1) v += __shfl_down(v, o, 64);
    __syncthreads();
    if ((t & 63) == 0) red[t >> 6] = v;
    __syncthreads();
    return red[0] + red[1] + red[2] + red[3];
}

// ---------------- weight transpose + bf16 convert: in[K][N] f32 -> out[N][K] bf16 ----------------
__global__ __launch_bounds__(256) void trans_kernel(
    const float* __restrict__ in, ushort* __restrict__ out,
    int K, int N, size_t in_z, size_t out_z) {
    __shared__ float T[32][33];
    in += blockIdx.z * in_z; out += blockIdx.z * out_z;
    int tx = threadIdx.x & 31, ty = threadIdx.x >> 5;
    int n0 = blockIdx.x * 32, k0 = blockIdx.y * 32;
    #pragma unroll
    for (int i = 0; i < 32; i += 8)
        T[ty + i][tx] = in[(size_t)(k0 + ty + i) * N + n0 + tx];
    __syncthreads();
    #pragma unroll
    for (int i = 0; i < 32; i += 8)
        out[(size_t)(n0 + ty + i) * K + k0 + tx] = f2bf(T[tx][ty + i]);
}

// ---------------- pack QKV bias ----------------
__global__ __launch_bounds__(256) void pack_bias_kernel(
    const float* __restrict__ bq, const float* __restrict__ bk,
    const float* __restrict__ bv, float* __restrict__ dst) {
    int i = blockIdx.x * 256 + threadIdx.x;
    if (i < HID) { dst[i] = bq[i]; dst[HID + i] = bk[i]; dst[2 * HID + i] = bv[i]; }
}

// ---------------- embedding + LN ----------------
__global__ __launch_bounds__(256) void embed_ln_kernel(
    const int* __restrict__ ids, const float* __restrict__ we,
    const float* __restrict__ pe, const float* __restrict__ ls,
    const float* __restrict__ lb, float* __restrict__ x, ushort* __restrict__ xb) {
    __shared__ float red[4];
    int srow = blockIdx.x, t = threadIdx.x;
    int id = ids[srow];
    float v[3];
    #pragma unroll
    for (int i = 0; i < 3; i++) {
        int hh = i * 256 + t;
        v[i] = we[(size_t)id * HID + hh] + pe[srow * HID + hh];
    }
    float mean = breduce(v[0] + v[1] + v[2], red) * (1.f / HID);
    __syncthreads();
    float sq = 0.f;
    #pragma unroll
    for (int i = 0; i < 3; i++) { float d = v[i] - mean; sq += d * d; }
    float var = breduce(sq, red) * (1.f / HID);
    float inv = rsqrtf(var + 1e-5f);
    #pragma unroll
    for (int i = 0; i < 3; i++) {
        int hh = i * 256 + t;
        float o = (v[i] - mean) * inv * ls[hh] + lb[hh];
        x[srow * HID + hh] = o;
        xb[srow * HID + hh] = f2bf(o);
    }
}

// ---------------- residual + LN ----------------
__global__ __launch_bounds__(256) void residual_ln_kernel(
    float* __restrict__ x, const float* __restrict__ y,
    const float* __restrict__ ls, const float* __restrict__ lb,
    ushort* __restrict__ xb) {
    __shared__ float red[4];
    int srow = blockIdx.x, t = threadIdx.x;
    float v[3];
    #pragma unroll
    for (int i = 0; i < 3; i++) {
        int hh = i * 256 + t;
        v[i] = x[srow * HID + hh] + y[srow * HID + hh];
    }
    float mean = breduce(v[0] + v[1] + v[2], red) * (1.f / HID);
    __syncthreads();
    float sq = 0.f;
    #pragma unroll
    for (int i = 0; i < 3; i++) { float d = v[i] - mean; sq += d * d; }
    float var = breduce(sq, red) * (1.f / HID);
    float inv = rsqrtf(var + 1e-5f);
    #pragma unroll
    for (int i = 0; i < 3; i++) {
        int hh = i * 256 + t;
        float o = (v[i] - mean) * inv * ls[hh] + lb[hh];
        x[srow * HID + hh] = o;
        xb[srow * HID + hh] = f2bf(o);
    }
}

// ---------------- bf16 MFMA GEMM ----------------
template<int ACT, int OUTF32, int OUTBF16>
__global__ __launch_bounds__(256) void gemm_mfma_kernel(
    const ushort* __restrict__ A, const ushort* __restrict__ Bt,
    const float* __restrict__ bias, float* __restrict__ C,
    ushort* __restrict__ Cb, int M, int N, int K) {
    __shared__ ushort As[128][40];
    __shared__ ushort Bs[128][40];
    int t = threadIdx.x;
    int lane = t & 63, wid = t >> 6;
    int m0 = blockIdx.y * 128, n0 = blockIdx.x * 128;
    int wr = (wid >> 1) * 64, wc = (wid & 1) * 64;
    fx4 acc[4][4];
    #pragma unroll
    for (int i = 0; i < 4; i++)
        #pragma unroll
        for (int j = 0; j < 4; j++) acc[i][j] = (fx4){0.f, 0.f, 0.f, 0.f};

    int rr = t >> 2, koff = (t & 3) * 8;
    const ushort* pa0 = A + (size_t)(m0 + rr) * K + koff;
    const ushort* pa1 = A + (size_t)(m0 + rr + 64) * K + koff;
    const ushort* pb0 = Bt + (size_t)(n0 + rr) * K + koff;
    const ushort* pb1 = Bt + (size_t)(n0 + rr + 64) * K + koff;

    for (int k0 = 0; k0 < K; k0 += 32) {
        *(uint4*)&As[rr][koff]      = *(const uint4*)(pa0 + k0);
        *(uint4*)&As[rr + 64][koff] = *(const uint4*)(pa1 + k0);
        *(uint4*)&Bs[rr][koff]      = *(const uint4*)(pb0 + k0);
        *(uint4*)&Bs[rr + 64][koff] = *(const uint4*)(pb1 + k0);
        __syncthreads();
        s16x8 a[4], b[4];
        #pragma unroll
        for (int f = 0; f < 4; f++) {
            a[f] = *(const s16x8*)&As[wr + f * 16 + (lane & 15)][(lane >> 4) * 8];
            b[f] = *(const s16x8*)&Bs[wc + f * 16 + (lane & 15)][(lane >> 4) * 8];
        }
        #pragma unroll
        for (int i = 0; i < 4; i++)
            #pragma unroll
            for (int j = 0; j < 4; j++)
                acc[i][j] = __builtin_amdgcn_mfma_f32_16x16x32_bf16(a[i], b[j], acc[i][j], 0, 0, 0);
        __syncthreads();
    }
    int crow = (lane >> 4) * 4, ccol = lane & 15;
    #pragma unroll
    for (int i = 0; i < 4; i++) {
        #pragma unroll
        for (int j = 0; j < 4; j++) {
            int col = n0 + wc + j * 16 + ccol;
            float bv_ = bias[col];
            #pragma unroll
            for (int r = 0; r < 4; r++) {
                int row = m0 + wr + i * 16 + crow + r;
                float val = acc[i][j][r] + bv_;
                if (ACT) {
                    float tt = 0.7978845608028654f * (val + 0.044715f * val * val * val);
                    val = val * (1.f / (1.f + __expf(-2.f * tt)));
                }
                if (OUTF32) C[(size_t)row * N + col] = val;
                if (OUTBF16) Cb[(size_t)row * N + col] = f2bf(val);
            }
        }
    }
}

// ---------------- MFMA flash band attention ----------------
// grid (S/64, H), 256 threads = 4 waves; wave w: 16 queries. 18 key-tiles of 32.
#define QB 64
#define KTW 32
#define NKT 18
__global__ __launch_bounds__(256) void band_attn_kernel(
    const ushort* __restrict__ qkv, const float* __restrict__ mask,
    ushort* __restrict__ ctxb) {
    __shared__ ushort Qs[QB][72];
    __shared__ ushort Ks[KTW][72];
    __shared__ ushort Vt[64][40];      // [dim][key]
    __shared__ ushort Ps[4][16][40];   // per-wave [query][key]
    __shared__ float  Ms[NKT * KTW];

    int h = blockIdx.y;
    int qbase = blockIdx.x * QB;
    int kbase = qbase - WIN;
    int t = threadIdx.x;
    int w = t >> 6, lane = t & 63;
    int lg = lane >> 4, lm = lane & 15;

    const ushort* qP = qkv + h * 64;
    const ushort* kP = qkv + HID + h * 64;
    const ushort* vP = qkv + 2 * HID + h * 64;

    {   // stage Q: 64 rows x 64 dims
        int r = t >> 2, c = (t & 3) * 16;
        const ushort* src = qP + (size_t)(qbase + r) * 2304 + c;
        *(uint4*)&Qs[r][c]     = *(const uint4*)src;
        *(uint4*)&Qs[r][c + 8] = *(const uint4*)(src + 8);
    }
    for (int i = t; i < NKT * KTW; i += 256) {
        int kp = kbase + i;
        Ms[i] = (kp >= 0 && kp < S_LEN && mask[kp] > 0.5f) ? 1.f : 0.f;
    }

    float mrun[4], lsum[4];
    #pragma unroll
    for (int r = 0; r < 4; r++) { mrun[r] = -1e30f; lsum[r] = 0.f; }
    fx4 accO[4];
    #pragma unroll
    for (int rt = 0; rt < 4; rt++) accO[rt] = (fx4){0.f, 0.f, 0.f, 0.f};

    int q0 = qbase + w * 16;
    const float scale = 0.125f;
    const fx4 zf = (fx4){0.f, 0.f, 0.f, 0.f};

    for (int kt = 0; kt < NKT; kt++) {
        __syncthreads();
        {   // stage K tile [32][64]
            int r = t >> 3, c = (t & 7) * 8;
            int kp = kbase + kt * KTW + r;
            uint4 val = {0u, 0u, 0u, 0u};
            if (kp >= 0 && kp < S_LEN) val = *(const uint4*)(kP + (size_t)kp * 2304 + c);
            *(uint4*)&Ks[r][c] = val;
        }
        {   // stage V transposed [dim][key]
            int key = t & 31, d0 = (t >> 5) * 8;
            int kp = kbase + kt * KTW + key;
            union { uint4 u; ushort s[8]; } cv;
            cv.u = (uint4){0u, 0u, 0u, 0u};
            if (kp >= 0 && kp < S_LEN) cv.u = *(const uint4*)(vP + (size_t)kp * 2304 + d0);
            #pragma unroll
            for (int j = 0; j < 8; j++) Vt[d0 + j][key] = cv.s[j];
        }
        __syncthreads();

        // QK^T: D[query(lg*4+r)][key(lm)+16ct]
        s16x8 aq0 = *(const s16x8*)&Qs[w * 16 + lm][lg * 8];
        s16x8 aq1 = *(const s16x8*)&Qs[w * 16 + lm][lg * 8 + 32];
        s16x8 bk0 = *(const s16x8*)&Ks[lm][lg * 8];
        s16x8 bk1 = *(const s16x8*)&Ks[lm][lg * 8 + 32];
        s16x8 bk2 = *(const s16x8*)&Ks[16 + lm][lg * 8];
        s16x8 bk3 = *(const s16x8*)&Ks[16 + lm][lg * 8 + 32];

        fx4 s0 = __builtin_amdgcn_mfma_f32_16x16x32_bf16(aq0, bk0, zf, 0, 0, 0);
        s0 = __builtin_amdgcn_mfma_f32_16x16x32_bf16(aq1, bk1, s0, 0, 0, 0);
        fx4 s1 = __builtin_amdgcn_mfma_f32_16x16x32_bf16(aq0, bk2, zf, 0, 0, 0);
        s1 = __builtin_amdgcn_mfma_f32_16x16x32_bf16(aq1, bk3, s1, 0, 0, 0);

        float tm[4];
        #pragma unroll
        for (int r = 0; r < 4; r++) {
            int qp = q0 + lg * 4 + r;
            int krel0 = kt * KTW + lm;
            int d0_ = kbase + krel0 - qp;
            bool ok0 = (d0_ >= -WIN) && (d0_ <= WIN) && (Ms[krel0] != 0.f);
            s0[r] = ok0 ? s0[r] * scale : -1e30f;
            int d1_ = d0_ + 16;
            bool ok1 = (d1_ >= -WIN) && (d1_ <= WIN) && (Ms[krel0 + 16] != 0.f);
            s1[r] = ok1 ? s1[r] * scale : -1e30f;
            tm[r] = fmaxf(s0[r], s1[r]);
        }
        #pragma unroll
        for (int r = 0; r < 4; r++)
            #pragma unroll
            for (int o = 1; o < 16; o <<= 1) tm[r] = fmaxf(tm[r], __shfl_xor(tm[r], o, 16));

        float corr[4];
        #pragma unroll
        for (int r = 0; r < 4; r++) {
            float nm = fmaxf(mrun[r], tm[r]);
            corr[r] = __expf(mrun[r] - nm);
            mrun[r] = nm;
            float p0 = __expf(s0[r] - nm); if (s0[r] < -1e29f) p0 = 0.f;
            float p1 = __expf(s1[r] - nm); if (s1[r] < -1e29f) p1 = 0.f;
            float rs = p0 + p1;
            #pragma unroll
            for (int o = 1; o < 16; o <<= 1) rs += __shfl_xor(rs, o, 16);
            lsum[r] = lsum[r] * corr[r] + rs;
            Ps[w][lg * 4 + r][lm]      = f2bf(p0);
            Ps[w][lg * 4 + r][16 + lm] = f2bf(p1);
        }
        // corr to O-layout (col query = lm)
        float c0 = __shfl(corr[0], (lm >> 2) * 16);
        float c1 = __shfl(corr[1], (lm >> 2) * 16);
        float c2 = __shfl(corr[2], (lm >> 2) * 16);
        float c3 = __shfl(corr[3], (lm >> 2) * 16);
        float cw = (lm & 2) ? ((lm & 1) ? c3 : c2) : ((lm & 1) ? c1 : c0);
        #pragma unroll
        for (int rt = 0; rt < 4; rt++) {
            accO[rt][0] *= cw; accO[rt][1] *= cw;
            accO[rt][2] *= cw; accO[rt][3] *= cw;
        }
        asm volatile("s_waitcnt lgkmcnt(0)" ::: "memory");
        // PV: O^T[dim][query], A=V^T frag, B=P frag
        s16x8 bp = *(const s16x8*)&Ps[w][lm][lg * 8];
        #pragma unroll
        for (int rt = 0; rt < 4; rt++) {
            s16x8 av = *(const s16x8*)&Vt[rt * 16 + lm][lg * 8];
            accO[rt] = __builtin_amdgcn_mfma_f32_16x16x32_bf16(av, bp, accO[rt], 0, 0, 0);
        }
    }

    float l0 = __shfl(lsum[0], (lm >> 2) * 16);
    float l1 = __shfl(lsum[1], (lm >> 2) * 16);
    float l2 = __shfl(lsum[2], (lm >> 2) * 16);
    float l3 = __shfl(lsum[3], (lm >> 2) * 16);
    float lw = (lm & 2) ? ((lm & 1) ? l3 : l2) : ((lm & 1) ? l1 : l0);
    float inv = 1.f / lw;
    int q = q0 + lm;
    #pragma unroll
    for (int rt = 0; rt < 4; rt++) {
        int dbase = rt * 16 + lg * 4;
        uint2 wv;
        wv.x = (uint)f2bf(accO[rt][0] * inv) | ((uint)f2bf(accO[rt][1] * inv) << 16);
        wv.y = (uint)f2bf(accO[rt][2] * inv) | ((uint)f2bf(accO[rt][3] * inv) << 16);
        *(uint2*)(ctxb + (size_t)q * HID + h * 64 + dbase) = wv;
    }
}

// ---------------- classifier head ----------------
__global__ __launch_bounds__(256) void head_logits_kernel(
    const float* __restrict__ x0, const float* __restrict__ Wt,
    const float* __restrict__ bias, float* __restrict__ out, int N) {
    __shared__ float p[HID];
    int t = threadIdx.x;
    for (int i = t; i < HID; i += 256) p[i] = x0[i];
    __syncthreads();
    int n = blockIdx.x * 256 + t;
    if (n < N) {
        float acc = bias[n];
        for (int hh = 0; hh < HID; hh++) acc += p[hh] * Wt[(size_t)hh * N + n];
        out[n] = acc;
    }
}

// ---------------- focal loss ----------------
__global__ __launch_bounds__(256) void focal_partial_kernel(
    const float* __restrict__ logits, const float* __restrict__ tgt,
    int N, float* __restrict__ partials) {
    __shared__ float red[256];
    int t = threadIdx.x;
    float s = 0.f;
    for (int i = blockIdx.x * 256 + t; i < N; i += gridDim.x * 256) {
        float l = logits[i], y = tgt[i];
        float bce = fmaxf(l, 0.f) - l * y + log1pf(expf(-fabsf(l)));
        float pt = expf(-bce);
        float om = 1.f - pt;
        s += om * om * bce;
    }
    red[t] = s;
    __syncthreads();
    for (int o = 128; o > 0; o >>= 1) {
        if (t < o) red[t] += red[t + o];
        __syncthreads();
    }
    if (t == 0) partials[blockIdx.x] = red[0];
}

__global__ void final_loss_kernel(const float* __restrict__ parts, float* __restrict__ out) {
    if (threadIdx.x == 0 && blockIdx.x == 0) {
        float a = 0.f, b = 0.f, c = 0.f;
        for (int i = 0; i < 32; i++) a += parts[i];
        for (int i = 0; i < 32; i++) b += parts[32 + i];
        for (int i = 0; i < 32; i++) c += parts[64 + i];
        out[0] = a / (float)N_ICD + b / (float)N_CPT + c / (float)N_CH;
    }
}

// ---------------- launch ----------------
extern "C" void kernel_launch(void* const* d_in, const int* in_sizes, int n_in,
                              void* d_out, int out_size, void* d_ws, size_t ws_size,
                              hipStream_t stream) {
    const int*   ids      = (const int*)d_in[0];
    const float* mask     = (const float*)d_in[1];
    const float* icd_lab  = (const float*)d_in[2];
    const float* cpt_lab  = (const float*)d_in[3];
    const float* ch_lab   = (const float*)d_in[4];
    const float* we       = (const float*)d_in[5];
    const float* pe       = (const float*)d_in[6];
    const float* els      = (const float*)d_in[7];
    const float* elb      = (const float*)d_in[8];
    const float* Wq       = (const float*)d_in[9];
    const float* bq       = (const float*)d_in[10];
    const float* Wk       = (const float*)d_in[11];
    const float* bk       = (const float*)d_in[12];
    const float* Wv       = (const float*)d_in[13];
    const float* bv       = (const float*)d_in[14];
    const float* Wo       = (const float*)d_in[15];
    const float* bo       = (const float*)d_in[16];
    const float* l1s      = (const float*)d_in[17];
    const float* l1b      = (const float*)d_in[18];
    const float* Wi       = (const float*)d_in[19];
    const float* bi       = (const float*)d_in[20];
    const float* Wo2      = (const float*)d_in[21];
    const float* bo2      = (const float*)d_in[22];
    const float* l2s      = (const float*)d_in[23];
    const float* l2b      = (const float*)d_in[24];
    const float* W_icd    = (const float*)d_in[25];
    const float* b_icd    = (const float*)d_in[26];
    const float* W_cpt    = (const float*)d_in[27];
    const float* b_cpt    = (const float*)d_in[28];
    const float* W_ch     = (const float*)d_in[29];
    const float* b_ch     = (const float*)d_in[30];

    const size_t SH = (size_t)S_LEN * HID;
    const size_t WW = (size_t)HID * HID;
    const size_t WI = (size_t)HID * FF;

    float* x     = (float*)d_ws;                  // SH
    float* tmp   = x + SH;                        // SH
    float* bqkv  = tmp + SH;                      // 2304
    float* chl   = bqkv + 2304;                   // 32
    float* parts = chl + 32;                      // 96
    ushort* xb      = (ushort*)(parts + 96);      // SH
    ushort* qkvb    = xb + SH;                    // S*2304
    ushort* ctxb    = qkvb + (size_t)S_LEN * 2304;// SH
    ushort* ffhb    = ctxb + SH;                  // S*FF
    ushort* wt_qkvo = ffhb + (size_t)S_LEN * FF;  // 8*WW
    ushort* wt_i    = wt_qkvo + 8 * WW;           // 2*WI
    ushort* wt_o2   = wt_i + 2 * WI;              // 2*WI

    float* out = (float*)d_out;
    float* icd_logits = out + 1;
    float* cpt_logits = out + 1 + N_ICD;

    trans_kernel<<<dim3(HID/32, HID/32, 2), 256, 0, stream>>>(Wq,  wt_qkvo + 0*WW, HID, HID, WW, 4*WW);
    trans_kernel<<<dim3(HID/32, HID/32, 2), 256, 0, stream>>>(Wk,  wt_qkvo + 1*WW, HID, HID, WW, 4*WW);
    trans_kernel<<<dim3(HID/32, HID/32, 2), 256, 0, stream>>>(Wv,  wt_qkvo + 2*WW, HID, HID, WW, 4*WW);
    trans_kernel<<<dim3(HID/32, HID/32, 2), 256, 0, stream>>>(Wo,  wt_qkvo + 3*WW, HID, HID, WW, 4*WW);
    trans_kernel<<<dim3(FF/32,  HID/32, 2), 256, 0, stream>>>(Wi,  wt_i,  HID, FF, WI, WI);
    trans_kernel<<<dim3(HID/32, FF/32,  2), 256, 0, stream>>>(Wo2, wt_o2, FF, HID, WI, WI);

    embed_ln_kernel<<<S_LEN, 256, 0, stream>>>(ids, we, pe, els, elb, x, xb);

    for (int l = 0; l < NLAYER; l++) {
        const ushort* wt_qkv_l = wt_qkvo + (size_t)l * 4 * WW;
        const ushort* wt_o_l   = wt_qkvo + (size_t)l * 4 * WW + 3 * WW;
        const ushort* wt_i_l   = wt_i  + (size_t)l * WI;
        const ushort* wt_o2_l  = wt_o2 + (size_t)l * WI;

        pack_bias_kernel<<<3, 256, 0, stream>>>(bq + l*HID, bk + l*HID, bv + l*HID, bqkv);
        gemm_mfma_kernel<0,0,1><<<dim3(2304/128, S_LEN/128), 256, 0, stream>>>(
            xb, wt_qkv_l, bqkv, nullptr, qkvb, S_LEN, 2304, HID);

        band_attn_kernel<<<dim3(S_LEN/QB, NHEAD), 256, 0, stream>>>(qkvb, mask, ctxb);

        gemm_mfma_kernel<0,1,0><<<dim3(HID/128, S_LEN/128), 256, 0, stream>>>(
            ctxb, wt_o_l, bo + l*HID, tmp, nullptr, S_LEN, HID, HID);
        residual_ln_kernel<<<S_LEN, 256, 0, stream>>>(x, tmp, l1s + l*HID, l1b + l*HID, xb);

        gemm_mfma_kernel<1,0,1><<<dim3(FF/128, S_LEN/128), 256, 0, stream>>>(
            xb, wt_i_l, bi + l*FF, nullptr, ffhb, S_LEN, FF, HID);
        gemm_mfma_kernel<0,1,0><<<dim3(HID/128, S_LEN/128), 256, 0, stream>>>(
            ffhb, wt_o2_l, bo2 + l*HID, tmp, nullptr, S_LEN, HID, FF);
        residual_ln_kernel<<<S_LEN, 256, 0, stream>>>(x, tmp, l2s + l*HID, l2b + l*HID, xb);
    }

    head_logits_kernel<<<(N_ICD + 255) / 256, 256, 0, stream>>>(x, W_icd, b_icd, icd_logits, N_ICD);
    head_logits_kernel<<<(N_CPT + 255) / 256, 256, 0, stream>>>(x, W_cpt, b_cpt, cpt_logits, N_CPT);
    head_logits_kernel<<<1, 256, 0, stream>>>(x, W_ch, b_ch, chl, N_CH);

    focal_partial_kernel<<<32, 256, 0, stream>>>(icd_logits, icd_lab, N_ICD, parts);
    focal_partial_kernel<<<32, 256, 0, stream>>>(cpt_logits, cpt_lab, N_CPT, parts + 32);
    focal_partial_kernel<<<32, 256, 0, stream>>>(chl, ch_lab, N_CH, parts + 64);
    final_loss_kernel<<<1, 1, 0, stream>>>(parts, out);
}

// Round 5
// 518.383 us; speedup vs baseline: 11.5539x; 1.2613x over previous
//
#include <hip/hip_runtime.h>
#include <hip/hip_bf16.h>
#include <math.h>

#define S_LEN 4096
#define HID 768
#define NHEAD 12
#define NLAYER 2
#define WIN 256
#define FF 3072
#define N_ICD 8000
#define N_CPT 5000
#define N_CH 22

typedef short s16x8 __attribute__((ext_vector_type(8)));
typedef float fx4 __attribute__((ext_vector_type(4)));

__device__ __forceinline__ ushort f2bf(float f) {
    union { float f; uint u; } c; c.f = f;
    uint u = c.u + 0x7fffu + ((c.u >> 16) & 1u);
    return (ushort)(u >> 16);
}

// async global->LDS, 16B per lane; l must be the wave-uniform base (HW adds lane*16)
__device__ __forceinline__ void gld_lds16(const ushort* g, ushort* l) {
    __builtin_amdgcn_global_load_lds(
        (const __attribute__((address_space(1))) unsigned int*)g,
        (__attribute__((address_space(3))) unsigned int*)l, 16, 0, 0);
}

// ---------------- block reduce (deterministic) ----------------
__device__ __forceinline__ float breduce(float v, volatile float* red) {
    int t = threadIdx.x;
    #pragma unroll
    for (int o = 32; o > 0; o >>= 1) v += __shfl_down(v, o, 64);
    __syncthreads();
    if ((t & 63) == 0) red[t >> 6] = v;
    __syncthreads();
    return red[0] + red[1] + red[2] + red[3];
}

// ---------------- weight transpose + bf16 convert: in[K][N] f32 -> out[N][K] bf16 ----------------
__global__ __launch_bounds__(256) void trans_kernel(
    const float* __restrict__ in, ushort* __restrict__ out,
    int K, int N, size_t in_z, size_t out_z) {
    __shared__ float T[32][33];
    in += blockIdx.z * in_z; out += blockIdx.z * out_z;
    int tx = threadIdx.x & 31, ty = threadIdx.x >> 5;
    int n0 = blockIdx.x * 32, k0 = blockIdx.y * 32;
    #pragma unroll
    for (int i = 0; i < 32; i += 8)
        T[ty + i][tx] = in[(size_t)(k0 + ty + i) * N + n0 + tx];
    __syncthreads();
    #pragma unroll
    for (int i = 0; i < 32; i += 8)
        out[(size_t)(n0 + ty + i) * K + k0 + tx] = f2bf(T[tx][ty + i]);
}

// ---------------- pack QKV bias ----------------
__global__ __launch_bounds__(256) void pack_bias_kernel(
    const float* __restrict__ bq, const float* __restrict__ bk,
    const float* __restrict__ bv, float* __restrict__ dst) {
    int i = blockIdx.x * 256 + threadIdx.x;
    if (i < HID) { dst[i] = bq[i]; dst[HID + i] = bk[i]; dst[2 * HID + i] = bv[i]; }
}

// ---------------- embedding + LN ----------------
__global__ __launch_bounds__(256) void embed_ln_kernel(
    const int* __restrict__ ids, const float* __restrict__ we,
    const float* __restrict__ pe, const float* __restrict__ ls,
    const float* __restrict__ lb, float* __restrict__ x, ushort* __restrict__ xb) {
    __shared__ float red[4];
    int srow = blockIdx.x, t = threadIdx.x;
    int id = ids[srow];
    float v[3];
    #pragma unroll
    for (int i = 0; i < 3; i++) {
        int hh = i * 256 + t;
        v[i] = we[(size_t)id * HID + hh] + pe[srow * HID + hh];
    }
    float mean = breduce(v[0] + v[1] + v[2], red) * (1.f / HID);
    __syncthreads();
    float sq = 0.f;
    #pragma unroll
    for (int i = 0; i < 3; i++) { float d = v[i] - mean; sq += d * d; }
    float var = breduce(sq, red) * (1.f / HID);
    float inv = rsqrtf(var + 1e-5f);
    #pragma unroll
    for (int i = 0; i < 3; i++) {
        int hh = i * 256 + t;
        float o = (v[i] - mean) * inv * ls[hh] + lb[hh];
        x[srow * HID + hh] = o;
        xb[srow * HID + hh] = f2bf(o);
    }
}

// ---------------- residual + LN ----------------
__global__ __launch_bounds__(256) void residual_ln_kernel(
    float* __restrict__ x, const float* __restrict__ y,
    const float* __restrict__ ls, const float* __restrict__ lb,
    ushort* __restrict__ xb) {
    __shared__ float red[4];
    int srow = blockIdx.x, t = threadIdx.x;
    float v[3];
    #pragma unroll
    for (int i = 0; i < 3; i++) {
        int hh = i * 256 + t;
        v[i] = x[srow * HID + hh] + y[srow * HID + hh];
    }
    float mean = breduce(v[0] + v[1] + v[2], red) * (1.f / HID);
    __syncthreads();
    float sq = 0.f;
    #pragma unroll
    for (int i = 0; i < 3; i++) { float d = v[i] - mean; sq += d * d; }
    float var = breduce(sq, red) * (1.f / HID);
    float inv = rsqrtf(var + 1e-5f);
    #pragma unroll
    for (int i = 0; i < 3; i++) {
        int hh = i * 256 + t;
        float o = (v[i] - mean) * inv * ls[hh] + lb[hh];
        x[srow * HID + hh] = o;
        xb[srow * HID + hh] = f2bf(o);
    }
}

// ---------------- bf16 MFMA GEMM, global_load_lds staging (m97 structure) ----------------
// BN=128: 4 waves 2x2, each 64x64. BN=64: 4 waves stacked on M, each 32x64.
template<int BN, int ACT, int OUTF32, int OUTBF16>
__global__ __launch_bounds__(256) void gemm_mfma_kernel(
    const ushort* __restrict__ A, const ushort* __restrict__ Bt,
    const float* __restrict__ bias, float* __restrict__ C,
    ushort* __restrict__ Cb, int M, int N, int K) {
    constexpr int MF = (BN == 128) ? 4 : 2;
    constexpr int NF = 4;
    __shared__ ushort As[128 * 32];
    __shared__ ushort Bs[BN * 32];
    int t = threadIdx.x;
    int lane = t & 63, wid = t >> 6;
    int lg = lane >> 4, lm = lane & 15;
    int m0 = blockIdx.y * 128, n0 = blockIdx.x * BN;
    int wr = (BN == 128) ? (wid >> 1) * 64 : wid * 32;
    int wc = (BN == 128) ? (wid & 1) * 64 : 0;

    fx4 acc[MF][NF];
    #pragma unroll
    for (int i = 0; i < MF; i++)
        #pragma unroll
        for (int j = 0; j < NF; j++) acc[i][j] = (fx4){0.f, 0.f, 0.f, 0.f};

    int lr = lane >> 2, lc = (lane & 3) * 8;
    const ushort* pa = A + (size_t)(m0 + wid * 32 + lr) * K + lc;
    ushort* la = As + wid * 1024;
    const ushort* pb;
    ushort* lb;
    if (BN == 128) { pb = Bt + (size_t)(n0 + wid * 32 + lr) * K + lc; lb = Bs + wid * 1024; }
    else           { pb = Bt + (size_t)(n0 + wid * 16 + lr) * K + lc; lb = Bs + wid * 512;  }

    for (int k0 = 0; k0 < K; k0 += 32) {
        gld_lds16(pa + k0, la);
        gld_lds16(pa + k0 + 16 * (size_t)K, la + 512);
        gld_lds16(pb + k0, lb);
        if (BN == 128) gld_lds16(pb + k0 + 16 * (size_t)K, lb + 512);
        __syncthreads();
        s16x8 a[MF], b[NF];
        #pragma unroll
        for (int f = 0; f < MF; f++)
            a[f] = *(const s16x8*)&As[(wr + f * 16 + lm) * 32 + lg * 8];
        #pragma unroll
        for (int f = 0; f < NF; f++)
            b[f] = *(const s16x8*)&Bs[(wc + f * 16 + lm) * 32 + lg * 8];
        #pragma unroll
        for (int i = 0; i < MF; i++)
            #pragma unroll
            for (int j = 0; j < NF; j++)
                acc[i][j] = __builtin_amdgcn_mfma_f32_16x16x32_bf16(a[i], b[j], acc[i][j], 0, 0, 0);
        __syncthreads();
    }
    int crow = lg * 4, ccol = lm;
    #pragma unroll
    for (int i = 0; i < MF; i++) {
        #pragma unroll
        for (int j = 0; j < NF; j++) {
            int col = n0 + wc + j * 16 + ccol;
            float bv_ = bias[col];
            #pragma unroll
            for (int r = 0; r < 4; r++) {
                int row = m0 + wr + i * 16 + crow + r;
                float val = acc[i][j][r] + bv_;
                if (ACT) {
                    float tt = 0.7978845608028654f * (val + 0.044715f * val * val * val);
                    val = val * (1.f / (1.f + __expf(-2.f * tt)));
                }
                if (OUTF32) C[(size_t)row * N + col] = val;
                if (OUTBF16) Cb[(size_t)row * N + col] = f2bf(val);
            }
        }
    }
}

// ---------------- MFMA flash band attention ----------------
#define QB 64
#define KTW 32
#define NKT 18
__global__ __launch_bounds__(256) void band_attn_kernel(
    const ushort* __restrict__ qkv, const float* __restrict__ mask,
    ushort* __restrict__ ctxb) {
    __shared__ ushort Qs[QB][72];
    __shared__ ushort Ks[KTW][72];
    __shared__ ushort Vt[64][40];
    __shared__ ushort Ps[4][16][40];
    __shared__ float  Ms[NKT * KTW];

    int h = blockIdx.y;
    int qbase = blockIdx.x * QB;
    int kbase = qbase - WIN;
    int t = threadIdx.x;
    int w = t >> 6, lane = t & 63;
    int lg = lane >> 4, lm = lane & 15;

    const ushort* qP = qkv + h * 64;
    const ushort* kP = qkv + HID + h * 64;
    const ushort* vP = qkv + 2 * HID + h * 64;

    {
        int r = t >> 2, c = (t & 3) * 16;
        const ushort* src = qP + (size_t)(qbase + r) * 2304 + c;
        *(uint4*)&Qs[r][c]     = *(const uint4*)src;
        *(uint4*)&Qs[r][c + 8] = *(const uint4*)(src + 8);
    }
    for (int i = t; i < NKT * KTW; i += 256) {
        int kp = kbase + i;
        Ms[i] = (kp >= 0 && kp < S_LEN && mask[kp] > 0.5f) ? 1.f : 0.f;
    }

    float mrun[4], lsum[4];
    #pragma unroll
    for (int r = 0; r < 4; r++) { mrun[r] = -1e30f; lsum[r] = 0.f; }
    fx4 accO[4];
    #pragma unroll
    for (int rt = 0; rt < 4; rt++) accO[rt] = (fx4){0.f, 0.f, 0.f, 0.f};

    int q0 = qbase + w * 16;
    const float scale = 0.125f;
    const fx4 zf = (fx4){0.f, 0.f, 0.f, 0.f};

    for (int kt = 0; kt < NKT; kt++) {
        __syncthreads();
        {
            int r = t >> 3, c = (t & 7) * 8;
            int kp = kbase + kt * KTW + r;
            uint4 val = {0u, 0u, 0u, 0u};
            if (kp >= 0 && kp < S_LEN) val = *(const uint4*)(kP + (size_t)kp * 2304 + c);
            *(uint4*)&Ks[r][c] = val;
        }
        {
            int key = t & 31, d0 = (t >> 5) * 8;
            int kp = kbase + kt * KTW + key;
            union { uint4 u; ushort s[8]; } cv;
            cv.u = (uint4){0u, 0u, 0u, 0u};
            if (kp >= 0 && kp < S_LEN) cv.u = *(const uint4*)(vP + (size_t)kp * 2304 + d0);
            #pragma unroll
            for (int j = 0; j < 8; j++) Vt[d0 + j][key] = cv.s[j];
        }
        __syncthreads();

        s16x8 aq0 = *(const s16x8*)&Qs[w * 16 + lm][lg * 8];
        s16x8 aq1 = *(const s16x8*)&Qs[w * 16 + lm][lg * 8 + 32];
        s16x8 bk0 = *(const s16x8*)&Ks[lm][lg * 8];
        s16x8 bk1 = *(const s16x8*)&Ks[lm][lg * 8 + 32];
        s16x8 bk2 = *(const s16x8*)&Ks[16 + lm][lg * 8];
        s16x8 bk3 = *(const s16x8*)&Ks[16 + lm][lg * 8 + 32];

        fx4 s0 = __builtin_amdgcn_mfma_f32_16x16x32_bf16(aq0, bk0, zf, 0, 0, 0);
        s0 = __builtin_amdgcn_mfma_f32_16x16x32_bf16(aq1, bk1, s0, 0, 0, 0);
        fx4 s1 = __builtin_amdgcn_mfma_f32_16x16x32_bf16(aq0, bk2, zf, 0, 0, 0);
        s1 = __builtin_amdgcn_mfma_f32_16x16x32_bf16(aq1, bk3, s1, 0, 0, 0);

        float tm[4];
        #pragma unroll
        for (int r = 0; r < 4; r++) {
            int qp = q0 + lg * 4 + r;
            int krel0 = kt * KTW + lm;
            int d0_ = kbase + krel0 - qp;
            bool ok0 = (d0_ >= -WIN) && (d0_ <= WIN) && (Ms[krel0] != 0.f);
            s0[r] = ok0 ? s0[r] * scale : -1e30f;
            int d1_ = d0_ + 16;
            bool ok1 = (d1_ >= -WIN) && (d1_ <= WIN) && (Ms[krel0 + 16] != 0.f);
            s1[r] = ok1 ? s1[r] * scale : -1e30f;
            tm[r] = fmaxf(s0[r], s1[r]);
        }
        #pragma unroll
        for (int r = 0; r < 4; r++)
            #pragma unroll
            for (int o = 1; o < 16; o <<= 1) tm[r] = fmaxf(tm[r], __shfl_xor(tm[r], o, 16));

        float corr[4];
        #pragma unroll
        for (int r = 0; r < 4; r++) {
            float nm = fmaxf(mrun[r], tm[r]);
            corr[r] = __expf(mrun[r] - nm);
            mrun[r] = nm;
            float p0 = __expf(s0[r] - nm); if (s0[r] < -1e29f) p0 = 0.f;
            float p1 = __expf(s1[r] - nm); if (s1[r] < -1e29f) p1 = 0.f;
            float rs = p0 + p1;
            #pragma unroll
            for (int o = 1; o < 16; o <<= 1) rs += __shfl_xor(rs, o, 16);
            lsum[r] = lsum[r] * corr[r] + rs;
            Ps[w][lg * 4 + r][lm]      = f2bf(p0);
            Ps[w][lg * 4 + r][16 + lm] = f2bf(p1);
        }
        float c0 = __shfl(corr[0], (lm >> 2) * 16);
        float c1 = __shfl(corr[1], (lm >> 2) * 16);
        float c2 = __shfl(corr[2], (lm >> 2) * 16);
        float c3 = __shfl(corr[3], (lm >> 2) * 16);
        float cw = (lm & 2) ? ((lm & 1) ? c3 : c2) : ((lm & 1) ? c1 : c0);
        #pragma unroll
        for (int rt = 0; rt < 4; rt++) {
            accO[rt][0] *= cw; accO[rt][1] *= cw;
            accO[rt][2] *= cw; accO[rt][3] *= cw;
        }
        asm volatile("s_waitcnt lgkmcnt(0)" ::: "memory");
        s16x8 bp = *(const s16x8*)&Ps[w][lm][lg * 8];
        #pragma unroll
        for (int rt = 0; rt < 4; rt++) {
            s16x8 av = *(const s16x8*)&Vt[rt * 16 + lm][lg * 8];
            accO[rt] = __builtin_amdgcn_mfma_f32_16x16x32_bf16(av, bp, accO[rt], 0, 0, 0);
        }
    }

    float l0 = __shfl(lsum[0], (lm >> 2) * 16);
    float l1 = __shfl(lsum[1], (lm >> 2) * 16);
    float l2 = __shfl(lsum[2], (lm >> 2) * 16);
    float l3 = __shfl(lsum[3], (lm >> 2) * 16);
    float lw = (lm & 2) ? ((lm & 1) ? l3 : l2) : ((lm & 1) ? l1 : l0);
    float inv = 1.f / lw;
    int q = q0 + lm;
    #pragma unroll
    for (int rt = 0; rt < 4; rt++) {
        int dbase = rt * 16 + lg * 4;
        uint2 wv;
        wv.x = (uint)f2bf(accO[rt][0] * inv) | ((uint)f2bf(accO[rt][1] * inv) << 16);
        wv.y = (uint)f2bf(accO[rt][2] * inv) | ((uint)f2bf(accO[rt][3] * inv) << 16);
        *(uint2*)(ctxb + (size_t)q * HID + h * 64 + dbase) = wv;
    }
}

// ---------------- head partial GEMV: part[kc][n] = sum over 96 K-elems ----------------
// grid (ceil(N/64), 8), block 256 = 64 cols x 4 k-subchunks of 24
__global__ __launch_bounds__(256) void head_partial_kernel(
    const float* __restrict__ x0, const float* __restrict__ Wt,
    float* __restrict__ part, int N) {
    __shared__ float red[256];
    int t = threadIdx.x;
    int nn = blockIdx.x * 64 + (t & 63);
    int ks = t >> 6;
    int kc = blockIdx.y;
    int h0 = kc * 96 + ks * 24;
    float s = 0.f;
    if (nn < N) {
        #pragma unroll
        for (int kk = 0; kk < 24; kk++)
            s += x0[h0 + kk] * Wt[(size_t)(h0 + kk) * N + nn];
    }
    red[t] = s;
    __syncthreads();
    if (t < 64 && nn < N)
        part[(size_t)kc * N + nn] = (red[t] + red[t + 64]) + (red[t + 128] + red[t + 192]);
}

// ---------------- combine partials + bias -> logits, fused focal partials ----------------
__global__ __launch_bounds__(256) void head_focal_kernel(
    const float* __restrict__ part, const float* __restrict__ bias,
    const float* __restrict__ tgt, int N,
    float* __restrict__ logits, float* __restrict__ partials) {
    __shared__ float red[256];
    int t = threadIdx.x;
    float s = 0.f;
    for (int i = blockIdx.x * 256 + t; i < N; i += gridDim.x * 256) {
        float l = bias[i];
        #pragma unroll
        for (int kc = 0; kc < 8; kc++) l += part[(size_t)kc * N + i];
        logits[i] = l;
        float y = tgt[i];
        float bce = fmaxf(l, 0.f) - l * y + log1pf(expf(-fabsf(l)));
        float pt = expf(-bce);
        float om = 1.f - pt;
        s += om * om * bce;
    }
    red[t] = s;
    __syncthreads();
    for (int o = 128; o > 0; o >>= 1) {
        if (t < o) red[t] += red[t + o];
        __syncthreads();
    }
    if (t == 0) partials[blockIdx.x] = red[0];
}

__global__ void final_loss_kernel(const float* __restrict__ parts, float* __restrict__ out) {
    if (threadIdx.x == 0 && blockIdx.x == 0) {
        float a = 0.f, b = 0.f, c;
        for (int i = 0; i < 16; i++) a += parts[i];
        for (int i = 0; i < 16; i++) b += parts[16 + i];
        c = parts[32];
        out[0] = a / (float)N_ICD + b / (float)N_CPT + c / (float)N_CH;
    }
}

// ---------------- launch ----------------
extern "C" void kernel_launch(void* const* d_in, const int* in_sizes, int n_in,
                              void* d_out, int out_size, void* d_ws, size_t ws_size,
                              hipStream_t stream) {
    const int*   ids      = (const int*)d_in[0];
    const float* mask     = (const float*)d_in[1];
    const float* icd_lab  = (const float*)d_in[2];
    const float* cpt_lab  = (const float*)d_in[3];
    const float* ch_lab   = (const float*)d_in[4];
    const float* we       = (const float*)d_in[5];
    const float* pe       = (const float*)d_in[6];
    const float* els      = (const float*)d_in[7];
    const float* elb      = (const float*)d_in[8];
    const float* Wq       = (const float*)d_in[9];
    const float* bq       = (const float*)d_in[10];
    const float* Wk       = (const float*)d_in[11];
    const float* bk       = (const float*)d_in[12];
    const float* Wv       = (const float*)d_in[13];
    const float* bv       = (const float*)d_in[14];
    const float* Wo       = (const float*)d_in[15];
    const float* bo       = (const float*)d_in[16];
    const float* l1s      = (const float*)d_in[17];
    const float* l1b      = (const float*)d_in[18];
    const float* Wi       = (const float*)d_in[19];
    const float* bi       = (const float*)d_in[20];
    const float* Wo2      = (const float*)d_in[21];
    const float* bo2      = (const float*)d_in[22];
    const float* l2s      = (const float*)d_in[23];
    const float* l2b      = (const float*)d_in[24];
    const float* W_icd    = (const float*)d_in[25];
    const float* b_icd    = (const float*)d_in[26];
    const float* W_cpt    = (const float*)d_in[27];
    const float* b_cpt    = (const float*)d_in[28];
    const float* W_ch     = (const float*)d_in[29];
    const float* b_ch     = (const float*)d_in[30];

    const size_t SH = (size_t)S_LEN * HID;
    const size_t WW = (size_t)HID * HID;
    const size_t WI = (size_t)HID * FF;

    char* base = (char*)d_ws;
    size_t off = 0;
    auto alloc = [&](size_t bytes) { void* p = base + off; off += (bytes + 255) & ~(size_t)255; return p; };

    float* x     = (float*)alloc(SH * 4);
    float* tmp   = (float*)alloc(SH * 4);
    float* bqkv  = (float*)alloc(2304 * 4);
    float* chl   = (float*)alloc(32 * 4);
    float* fpart = (float*)alloc(64 * 4);
    float* hp_icd = (float*)alloc((size_t)8 * N_ICD * 4);
    float* hp_cpt = (float*)alloc((size_t)8 * N_CPT * 4);
    float* hp_ch  = (float*)alloc((size_t)8 * 32 * 4);
    ushort* xb      = (ushort*)alloc(SH * 2);
    ushort* qkvb    = (ushort*)alloc((size_t)S_LEN * 2304 * 2);
    ushort* ctxb    = (ushort*)alloc(SH * 2);
    ushort* ffhb    = (ushort*)alloc((size_t)S_LEN * FF * 2);
    ushort* wt_qkvo = (ushort*)alloc((size_t)8 * WW * 2);
    ushort* wt_i    = (ushort*)alloc((size_t)2 * WI * 2);
    ushort* wt_o2   = (ushort*)alloc((size_t)2 * WI * 2);

    float* out = (float*)d_out;
    float* icd_logits = out + 1;
    float* cpt_logits = out + 1 + N_ICD;

    trans_kernel<<<dim3(HID/32, HID/32, 2), 256, 0, stream>>>(Wq,  wt_qkvo + 0*WW, HID, HID, WW, 4*WW);
    trans_kernel<<<dim3(HID/32, HID/32, 2), 256, 0, stream>>>(Wk,  wt_qkvo + 1*WW, HID, HID, WW, 4*WW);
    trans_kernel<<<dim3(HID/32, HID/32, 2), 256, 0, stream>>>(Wv,  wt_qkvo + 2*WW, HID, HID, WW, 4*WW);
    trans_kernel<<<dim3(HID/32, HID/32, 2), 256, 0, stream>>>(Wo,  wt_qkvo + 3*WW, HID, HID, WW, 4*WW);
    trans_kernel<<<dim3(FF/32,  HID/32, 2), 256, 0, stream>>>(Wi,  wt_i,  HID, FF, WI, WI);
    trans_kernel<<<dim3(HID/32, FF/32,  2), 256, 0, stream>>>(Wo2, wt_o2, FF, HID, WI, WI);

    embed_ln_kernel<<<S_LEN, 256, 0, stream>>>(ids, we, pe, els, elb, x, xb);

    for (int l = 0; l < NLAYER; l++) {
        const ushort* wt_qkv_l = wt_qkvo + (size_t)l * 4 * WW;
        const ushort* wt_o_l   = wt_qkvo + (size_t)l * 4 * WW + 3 * WW;
        const ushort* wt_i_l   = wt_i  + (size_t)l * WI;
        const ushort* wt_o2_l  = wt_o2 + (size_t)l * WI;

        pack_bias_kernel<<<3, 256, 0, stream>>>(bq + l*HID, bk + l*HID, bv + l*HID, bqkv);
        gemm_mfma_kernel<128,0,0,1><<<dim3(2304/128, S_LEN/128), 256, 0, stream>>>(
            xb, wt_qkv_l, bqkv, nullptr, qkvb, S_LEN, 2304, HID);

        band_attn_kernel<<<dim3(S_LEN/QB, NHEAD), 256, 0, stream>>>(qkvb, mask, ctxb);

        gemm_mfma_kernel<64,0,1,0><<<dim3(HID/64, S_LEN/128), 256, 0, stream>>>(
            ctxb, wt_o_l, bo + l*HID, tmp, nullptr, S_LEN, HID, HID);
        residual_ln_kernel<<<S_LEN, 256, 0, stream>>>(x, tmp, l1s + l*HID, l1b + l*HID, xb);

        gemm_mfma_kernel<128,1,0,1><<<dim3(FF/128, S_LEN/128), 256, 0, stream>>>(
            xb, wt_i_l, bi + l*FF, nullptr, ffhb, S_LEN, FF, HID);
        gemm_mfma_kernel<64,0,1,0><<<dim3(HID/64, S_LEN/128), 256, 0, stream>>>(
            ffhb, wt_o2_l, bo2 + l*HID, tmp, nullptr, S_LEN, HID, FF);
        residual_ln_kernel<<<S_LEN, 256, 0, stream>>>(x, tmp, l2s + l*HID, l2b + l*HID, xb);
    }

    // heads: split-K partial GEMV (x row 0 is pooled), then combine+focal
    head_partial_kernel<<<dim3((N_ICD + 63) / 64, 8), 256, 0, stream>>>(x, W_icd, hp_icd, N_ICD);
    head_partial_kernel<<<dim3((N_CPT + 63) / 64, 8), 256, 0, stream>>>(x, W_cpt, hp_cpt, N_CPT);
    head_partial_kernel<<<dim3(1, 8), 256, 0, stream>>>(x, W_ch, hp_ch, N_CH);

    head_focal_kernel<<<16, 256, 0, stream>>>(hp_icd, b_icd, icd_lab, N_ICD, icd_logits, fpart);
    head_focal_kernel<<<16, 256, 0, stream>>>(hp_cpt, b_cpt, cpt_lab, N_CPT, cpt_logits, fpart + 16);
    head_focal_kernel<<<1, 256, 0, stream>>>(hp_ch, b_ch, ch_lab, N_CH, chl, fpart + 32);

    final_loss_kernel<<<1, 1, 0, stream>>>(fpart, out);
}

// Round 6
// 495.215 us; speedup vs baseline: 12.0944x; 1.0468x over previous
//
#include <hip/hip_runtime.h>
#include <hip/hip_bf16.h>
#include <math.h>

#define S_LEN 4096
#define HID 768
#define NHEAD 12
#define NLAYER 2
#define WIN 256
#define FF 3072
#define N_ICD 8000
#define N_CPT 5000
#define N_CH 22

typedef short s16x8 __attribute__((ext_vector_type(8)));
typedef float fx4 __attribute__((ext_vector_type(4)));

__device__ __forceinline__ ushort f2bf(float f) {
    union { float f; uint u; } c; c.f = f;
    uint u = c.u + 0x7fffu + ((c.u >> 16) & 1u);
    return (ushort)(u >> 16);
}

// async global->LDS, 16B per lane; l must be the wave-uniform base (HW adds lane*16)
__device__ __forceinline__ void gld_lds16(const ushort* g, ushort* l) {
    __builtin_amdgcn_global_load_lds(
        (const __attribute__((address_space(1))) unsigned int*)g,
        (__attribute__((address_space(3))) unsigned int*)l, 16, 0, 0);
}

// ---------------- block reduce (deterministic) ----------------
__device__ __forceinline__ float breduce(float v, volatile float* red) {
    int t = threadIdx.x;
    #pragma unroll
    for (int o = 32; o > 0; o >>= 1) v += __shfl_down(v, o, 64);
    __syncthreads();
    if ((t & 63) == 0) red[t >> 6] = v;
    __syncthreads();
    return red[0] + red[1] + red[2] + red[3];
}

// ---------------- weight transpose + bf16 convert: in[K][N] f32 -> out[N][K] bf16 ----------------
__global__ __launch_bounds__(256) void trans_kernel(
    const float* __restrict__ in, ushort* __restrict__ out,
    int K, int N, size_t in_z, size_t out_z) {
    __shared__ float T[32][33];
    in += blockIdx.z * in_z; out += blockIdx.z * out_z;
    int tx = threadIdx.x & 31, ty = threadIdx.x >> 5;
    int n0 = blockIdx.x * 32, k0 = blockIdx.y * 32;
    #pragma unroll
    for (int i = 0; i < 32; i += 8)
        T[ty + i][tx] = in[(size_t)(k0 + ty + i) * N + n0 + tx];
    __syncthreads();
    #pragma unroll
    for (int i = 0; i < 32; i += 8)
        out[(size_t)(n0 + ty + i) * K + k0 + tx] = f2bf(T[tx][ty + i]);
}

// ---------------- pack QKV bias ----------------
__global__ __launch_bounds__(256) void pack_bias_kernel(
    const float* __restrict__ bq, const float* __restrict__ bk,
    const float* __restrict__ bv, float* __restrict__ dst) {
    int i = blockIdx.x * 256 + threadIdx.x;
    if (i < HID) { dst[i] = bq[i]; dst[HID + i] = bk[i]; dst[2 * HID + i] = bv[i]; }
}

// ---------------- embedding + LN ----------------
__global__ __launch_bounds__(256) void embed_ln_kernel(
    const int* __restrict__ ids, const float* __restrict__ we,
    const float* __restrict__ pe, const float* __restrict__ ls,
    const float* __restrict__ lb, float* __restrict__ x, ushort* __restrict__ xb) {
    __shared__ float red[4];
    int srow = blockIdx.x, t = threadIdx.x;
    int id = ids[srow];
    float v[3];
    #pragma unroll
    for (int i = 0; i < 3; i++) {
        int hh = i * 256 + t;
        v[i] = we[(size_t)id * HID + hh] + pe[srow * HID + hh];
    }
    float mean = breduce(v[0] + v[1] + v[2], red) * (1.f / HID);
    __syncthreads();
    float sq = 0.f;
    #pragma unroll
    for (int i = 0; i < 3; i++) { float d = v[i] - mean; sq += d * d; }
    float var = breduce(sq, red) * (1.f / HID);
    float inv = rsqrtf(var + 1e-5f);
    #pragma unroll
    for (int i = 0; i < 3; i++) {
        int hh = i * 256 + t;
        float o = (v[i] - mean) * inv * ls[hh] + lb[hh];
        x[srow * HID + hh] = o;
        xb[srow * HID + hh] = f2bf(o);
    }
}

// ---------------- residual + LN ----------------
__global__ __launch_bounds__(256) void residual_ln_kernel(
    float* __restrict__ x, const float* __restrict__ y,
    const float* __restrict__ ls, const float* __restrict__ lb,
    ushort* __restrict__ xb) {
    __shared__ float red[4];
    int srow = blockIdx.x, t = threadIdx.x;
    float v[3];
    #pragma unroll
    for (int i = 0; i < 3; i++) {
        int hh = i * 256 + t;
        v[i] = x[srow * HID + hh] + y[srow * HID + hh];
    }
    float mean = breduce(v[0] + v[1] + v[2], red) * (1.f / HID);
    __syncthreads();
    float sq = 0.f;
    #pragma unroll
    for (int i = 0; i < 3; i++) { float d = v[i] - mean; sq += d * d; }
    float var = breduce(sq, red) * (1.f / HID);
    float inv = rsqrtf(var + 1e-5f);
    #pragma unroll
    for (int i = 0; i < 3; i++) {
        int hh = i * 256 + t;
        float o = (v[i] - mean) * inv * ls[hh] + lb[hh];
        x[srow * HID + hh] = o;
        xb[srow * HID + hh] = f2bf(o);
    }
}

// ---------------- bf16 MFMA GEMM, global_load_lds staging, BK=64 ----------------
// BN=128: 4 waves 2x2, each 64x64. BN=64: 4 waves stacked on M, each 32x64.
template<int BN, int ACT, int OUTF32, int OUTBF16>
__global__ __launch_bounds__(256) void gemm_mfma_kernel(
    const ushort* __restrict__ A, const ushort* __restrict__ Bt,
    const float* __restrict__ bias, float* __restrict__ C,
    ushort* __restrict__ Cb, int M, int N, int K) {
    constexpr int MF = (BN == 128) ? 4 : 2;
    constexpr int NF = 4;
    constexpr int NBG = (BN == 128) ? 4 : 2;   // B gld groups per wave
    __shared__ ushort As[128 * 64];
    __shared__ ushort Bs[BN * 64];
    int t = threadIdx.x;
    int lane = t & 63, wid = t >> 6;
    int lg = lane >> 4, lm = lane & 15;
    int m0 = blockIdx.y * 128, n0 = blockIdx.x * BN;
    int wr = (BN == 128) ? (wid >> 1) * 64 : wid * 32;
    int wc = (BN == 128) ? (wid & 1) * 64 : 0;

    fx4 acc[MF][NF];
    #pragma unroll
    for (int i = 0; i < MF; i++)
        #pragma unroll
        for (int j = 0; j < NF; j++) acc[i][j] = (fx4){0.f, 0.f, 0.f, 0.f};

    // staging: 8-row groups; lane l -> row +l>>3, kcol (l&7)*8 (matches linear LDS)
    int srow = lane >> 3, scol = (lane & 7) * 8;
    const ushort* paw = A + (size_t)(m0 + wid * 32 + srow) * K + scol;
    ushort* law = As + wid * 32 * 64;
    const ushort* pbw = Bt + (size_t)(n0 + wid * 8 * NBG + srow) * K + scol;
    ushort* lbw = Bs + wid * 8 * NBG * 64;

    for (int k0 = 0; k0 < K; k0 += 64) {
        #pragma unroll
        for (int i = 0; i < 4; i++)
            gld_lds16(paw + (size_t)i * 8 * K + k0, law + i * 512);
        #pragma unroll
        for (int i = 0; i < NBG; i++)
            gld_lds16(pbw + (size_t)i * 8 * K + k0, lbw + i * 512);
        __syncthreads();
        #pragma unroll
        for (int ks = 0; ks < 2; ks++) {
            s16x8 a[MF], b[NF];
            #pragma unroll
            for (int f = 0; f < MF; f++)
                a[f] = *(const s16x8*)&As[(wr + f * 16 + lm) * 64 + ks * 32 + lg * 8];
            #pragma unroll
            for (int f = 0; f < NF; f++)
                b[f] = *(const s16x8*)&Bs[(wc + f * 16 + lm) * 64 + ks * 32 + lg * 8];
            #pragma unroll
            for (int i = 0; i < MF; i++)
                #pragma unroll
                for (int j = 0; j < NF; j++)
                    acc[i][j] = __builtin_amdgcn_mfma_f32_16x16x32_bf16(a[i], b[j], acc[i][j], 0, 0, 0);
        }
        __syncthreads();
    }
    int crow = lg * 4, ccol = lm;
    #pragma unroll
    for (int i = 0; i < MF; i++) {
        #pragma unroll
        for (int j = 0; j < NF; j++) {
            int col = n0 + wc + j * 16 + ccol;
            float bv_ = bias[col];
            #pragma unroll
            for (int r = 0; r < 4; r++) {
                int row = m0 + wr + i * 16 + crow + r;
                float val = acc[i][j][r] + bv_;
                if (ACT) {
                    float tt = 0.7978845608028654f * (val + 0.044715f * val * val * val);
                    val = val * (1.f / (1.f + __expf(-2.f * tt)));
                }
                if (OUTF32) C[(size_t)row * N + col] = val;
                if (OUTBF16) Cb[(size_t)row * N + col] = f2bf(val);
            }
        }
    }
}

// ---------------- MFMA flash band attention, KTW=64 ----------------
#define QB 64
#define KTW 64
#define NKT 9
__global__ __launch_bounds__(256) void band_attn_kernel(
    const ushort* __restrict__ qkv, const float* __restrict__ mask,
    ushort* __restrict__ ctxb) {
    __shared__ ushort Qs[QB][72];
    __shared__ ushort Ks[KTW][72];
    __shared__ ushort Vt[64][72];
    __shared__ ushort Ps[4][16][72];
    __shared__ float  Ms[NKT * KTW];

    int h = blockIdx.y;
    int qbase = blockIdx.x * QB;
    int kbase = qbase - WIN;
    int t = threadIdx.x;
    int w = t >> 6, lane = t & 63;
    int lg = lane >> 4, lm = lane & 15;

    const ushort* qP = qkv + h * 64;
    const ushort* kP = qkv + HID + h * 64;
    const ushort* vP = qkv + 2 * HID + h * 64;

    {   // stage Q: 64 rows x 64 dims
        int r = t >> 2, c = (t & 3) * 16;
        const ushort* src = qP + (size_t)(qbase + r) * 2304 + c;
        *(uint4*)&Qs[r][c]     = *(const uint4*)src;
        *(uint4*)&Qs[r][c + 8] = *(const uint4*)(src + 8);
    }
    for (int i = t; i < NKT * KTW; i += 256) {
        int kp = kbase + i;
        Ms[i] = (kp >= 0 && kp < S_LEN && mask[kp] > 0.5f) ? 1.f : 0.f;
    }

    float mrun[4], lsum[4];
    #pragma unroll
    for (int r = 0; r < 4; r++) { mrun[r] = -1e30f; lsum[r] = 0.f; }
    fx4 accO[4];
    #pragma unroll
    for (int rt = 0; rt < 4; rt++) accO[rt] = (fx4){0.f, 0.f, 0.f, 0.f};

    int q0 = qbase + w * 16;
    const float scale = 0.125f;
    const fx4 zf = (fx4){0.f, 0.f, 0.f, 0.f};

    for (int kt = 0; kt < NKT; kt++) {
        __syncthreads();
        {   // stage K tile [64][64]
            int r = t >> 2, c = (t & 3) * 16;
            int kp = kbase + kt * KTW + r;
            uint4 v0 = {0u,0u,0u,0u}, v1 = {0u,0u,0u,0u};
            if (kp >= 0 && kp < S_LEN) {
                const ushort* ks = kP + (size_t)kp * 2304 + c;
                v0 = *(const uint4*)ks; v1 = *(const uint4*)(ks + 8);
            }
            *(uint4*)&Ks[r][c] = v0; *(uint4*)&Ks[r][c + 8] = v1;
        }
        {   // stage V transposed [dim][key]: thread -> key=lane, dims w*16..w*16+15
            int key = t & 63, d0 = (t >> 6) * 16;
            int kp = kbase + kt * KTW + key;
            union { uint4 u; ushort s[8]; } c0, c1;
            c0.u = (uint4){0u,0u,0u,0u}; c1.u = c0.u;
            if (kp >= 0 && kp < S_LEN) {
                const ushort* vs = vP + (size_t)kp * 2304 + d0;
                c0.u = *(const uint4*)vs; c1.u = *(const uint4*)(vs + 8);
            }
            #pragma unroll
            for (int j = 0; j < 8; j++) Vt[d0 + j][key] = c0.s[j];
            #pragma unroll
            for (int j = 0; j < 8; j++) Vt[d0 + 8 + j][key] = c1.s[j];
        }
        __syncthreads();

        // QK^T: D[query(lg*4+r)][key j*16+lm]
        s16x8 aq0 = *(const s16x8*)&Qs[w * 16 + lm][lg * 8];
        s16x8 aq1 = *(const s16x8*)&Qs[w * 16 + lm][lg * 8 + 32];
        fx4 sc[4];
        #pragma unroll
        for (int j = 0; j < 4; j++) {
            s16x8 b0 = *(const s16x8*)&Ks[j * 16 + lm][lg * 8];
            s16x8 b1 = *(const s16x8*)&Ks[j * 16 + lm][lg * 8 + 32];
            sc[j] = __builtin_amdgcn_mfma_f32_16x16x32_bf16(aq0, b0, zf, 0, 0, 0);
            sc[j] = __builtin_amdgcn_mfma_f32_16x16x32_bf16(aq1, b1, sc[j], 0, 0, 0);
        }

        float tm[4];
        #pragma unroll
        for (int r = 0; r < 4; r++) {
            int qp = q0 + lg * 4 + r;
            tm[r] = -1e30f;
            #pragma unroll
            for (int j = 0; j < 4; j++) {
                int krel = kt * KTW + j * 16 + lm;
                int dd = kbase + krel - qp;
                bool ok = (dd >= -WIN) && (dd <= WIN) && (Ms[krel] != 0.f);
                sc[j][r] = ok ? sc[j][r] * scale : -1e30f;
                tm[r] = fmaxf(tm[r], sc[j][r]);
            }
        }
        #pragma unroll
        for (int r = 0; r < 4; r++)
            #pragma unroll
            for (int o = 1; o < 16; o <<= 1) tm[r] = fmaxf(tm[r], __shfl_xor(tm[r], o, 16));

        float corr[4];
        #pragma unroll
        for (int r = 0; r < 4; r++) {
            float nm = fmaxf(mrun[r], tm[r]);
            corr[r] = __expf(mrun[r] - nm);
            mrun[r] = nm;
            float p[4], rs = 0.f;
            #pragma unroll
            for (int j = 0; j < 4; j++) {
                p[j] = __expf(sc[j][r] - nm);
                if (sc[j][r] < -1e29f) p[j] = 0.f;
                rs += p[j];
            }
            #pragma unroll
            for (int o = 1; o < 16; o <<= 1) rs += __shfl_xor(rs, o, 16);
            lsum[r] = lsum[r] * corr[r] + rs;
            #pragma unroll
            for (int j = 0; j < 4; j++)
                Ps[w][lg * 4 + r][j * 16 + lm] = f2bf(p[j]);
        }
        // corr to O-layout (col query = lm)
        float c0 = __shfl(corr[0], (lm >> 2) * 16);
        float c1 = __shfl(corr[1], (lm >> 2) * 16);
        float c2 = __shfl(corr[2], (lm >> 2) * 16);
        float c3 = __shfl(corr[3], (lm >> 2) * 16);
        float cw = (lm & 2) ? ((lm & 1) ? c3 : c2) : ((lm & 1) ? c1 : c0);
        #pragma unroll
        for (int rt = 0; rt < 4; rt++) {
            accO[rt][0] *= cw; accO[rt][1] *= cw;
            accO[rt][2] *= cw; accO[rt][3] *= cw;
        }
        asm volatile("s_waitcnt lgkmcnt(0)" ::: "memory");
        // PV: O^T[dim][query], A=V^T frags, B=P frags, two k-halves
        s16x8 bp0 = *(const s16x8*)&Ps[w][lm][lg * 8];
        s16x8 bp1 = *(const s16x8*)&Ps[w][lm][lg * 8 + 32];
        #pragma unroll
        for (int rt = 0; rt < 4; rt++) {
            s16x8 av0 = *(const s16x8*)&Vt[rt * 16 + lm][lg * 8];
            s16x8 av1 = *(const s16x8*)&Vt[rt * 16 + lm][lg * 8 + 32];
            accO[rt] = __builtin_amdgcn_mfma_f32_16x16x32_bf16(av0, bp0, accO[rt], 0, 0, 0);
            accO[rt] = __builtin_amdgcn_mfma_f32_16x16x32_bf16(av1, bp1, accO[rt], 0, 0, 0);
        }
    }

    float l0 = __shfl(lsum[0], (lm >> 2) * 16);
    float l1 = __shfl(lsum[1], (lm >> 2) * 16);
    float l2 = __shfl(lsum[2], (lm >> 2) * 16);
    float l3 = __shfl(lsum[3], (lm >> 2) * 16);
    float lw = (lm & 2) ? ((lm & 1) ? l3 : l2) : ((lm & 1) ? l1 : l0);
    float inv = 1.f / lw;
    int q = q0 + lm;
    #pragma unroll
    for (int rt = 0; rt < 4; rt++) {
        int dbase = rt * 16 + lg * 4;
        uint2 wv;
        wv.x = (uint)f2bf(accO[rt][0] * inv) | ((uint)f2bf(accO[rt][1] * inv) << 16);
        wv.y = (uint)f2bf(accO[rt][2] * inv) | ((uint)f2bf(accO[rt][3] * inv) << 16);
        *(uint2*)(ctxb + (size_t)q * HID + h * 64 + dbase) = wv;
    }
}

// ---------------- head partial GEMV ----------------
__global__ __launch_bounds__(256) void head_partial_kernel(
    const float* __restrict__ x0, const float* __restrict__ Wt,
    float* __restrict__ part, int N) {
    __shared__ float red[256];
    int t = threadIdx.x;
    int nn = blockIdx.x * 64 + (t & 63);
    int ks = t >> 6;
    int kc = blockIdx.y;
    int h0 = kc * 96 + ks * 24;
    float s = 0.f;
    if (nn < N) {
        #pragma unroll
        for (int kk = 0; kk < 24; kk++)
            s += x0[h0 + kk] * Wt[(size_t)(h0 + kk) * N + nn];
    }
    red[t] = s;
    __syncthreads();
    if (t < 64 && nn < N)
        part[(size_t)kc * N + nn] = (red[t] + red[t + 64]) + (red[t + 128] + red[t + 192]);
}

// ---------------- combine partials + bias -> logits, fused focal partials ----------------
__global__ __launch_bounds__(256) void head_focal_kernel(
    const float* __restrict__ part, const float* __restrict__ bias,
    const float* __restrict__ tgt, int N,
    float* __restrict__ logits, float* __restrict__ partials) {
    __shared__ float red[256];
    int t = threadIdx.x;
    float s = 0.f;
    for (int i = blockIdx.x * 256 + t; i < N; i += gridDim.x * 256) {
        float l = bias[i];
        #pragma unroll
        for (int kc = 0; kc < 8; kc++) l += part[(size_t)kc * N + i];
        logits[i] = l;
        float y = tgt[i];
        float bce = fmaxf(l, 0.f) - l * y + log1pf(expf(-fabsf(l)));
        float pt = expf(-bce);
        float om = 1.f - pt;
        s += om * om * bce;
    }
    red[t] = s;
    __syncthreads();
    for (int o = 128; o > 0; o >>= 1) {
        if (t < o) red[t] += red[t + o];
        __syncthreads();
    }
    if (t == 0) partials[blockIdx.x] = red[0];
}

__global__ void final_loss_kernel(const float* __restrict__ parts, float* __restrict__ out) {
    if (threadIdx.x == 0 && blockIdx.x == 0) {
        float a = 0.f, b = 0.f, c;
        for (int i = 0; i < 16; i++) a += parts[i];
        for (int i = 0; i < 16; i++) b += parts[16 + i];
        c = parts[32];
        out[0] = a / (float)N_ICD + b / (float)N_CPT + c / (float)N_CH;
    }
}

// ---------------- launch ----------------
extern "C" void kernel_launch(void* const* d_in, const int* in_sizes, int n_in,
                              void* d_out, int out_size, void* d_ws, size_t ws_size,
                              hipStream_t stream) {
    const int*   ids      = (const int*)d_in[0];
    const float* mask     = (const float*)d_in[1];
    const float* icd_lab  = (const float*)d_in[2];
    const float* cpt_lab  = (const float*)d_in[3];
    const float* ch_lab   = (const float*)d_in[4];
    const float* we       = (const float*)d_in[5];
    const float* pe       = (const float*)d_in[6];
    const float* els      = (const float*)d_in[7];
    const float* elb      = (const float*)d_in[8];
    const float* Wq       = (const float*)d_in[9];
    const float* bq       = (const float*)d_in[10];
    const float* Wk       = (const float*)d_in[11];
    const float* bk       = (const float*)d_in[12];
    const float* Wv       = (const float*)d_in[13];
    const float* bv       = (const float*)d_in[14];
    const float* Wo       = (const float*)d_in[15];
    const float* bo       = (const float*)d_in[16];
    const float* l1s      = (const float*)d_in[17];
    const float* l1b      = (const float*)d_in[18];
    const float* Wi       = (const float*)d_in[19];
    const float* bi       = (const float*)d_in[20];
    const float* Wo2      = (const float*)d_in[21];
    const float* bo2      = (const float*)d_in[22];
    const float* l2s      = (const float*)d_in[23];
    const float* l2b      = (const float*)d_in[24];
    const float* W_icd    = (const float*)d_in[25];
    const float* b_icd    = (const float*)d_in[26];
    const float* W_cpt    = (const float*)d_in[27];
    const float* b_cpt    = (const float*)d_in[28];
    const float* W_ch     = (const float*)d_in[29];
    const float* b_ch     = (const float*)d_in[30];

    const size_t SH = (size_t)S_LEN * HID;
    const size_t WW = (size_t)HID * HID;
    const size_t WI = (size_t)HID * FF;

    char* base = (char*)d_ws;
    size_t off = 0;
    auto alloc = [&](size_t bytes) { void* p = base + off; off += (bytes + 255) & ~(size_t)255; return p; };

    float* x     = (float*)alloc(SH * 4);
    float* tmp   = (float*)alloc(SH * 4);
    float* bqkv  = (float*)alloc(2304 * 4);
    float* chl   = (float*)alloc(32 * 4);
    float* fpart = (float*)alloc(64 * 4);
    float* hp_icd = (float*)alloc((size_t)8 * N_ICD * 4);
    float* hp_cpt = (float*)alloc((size_t)8 * N_CPT * 4);
    float* hp_ch  = (float*)alloc((size_t)8 * 32 * 4);
    ushort* xb      = (ushort*)alloc(SH * 2);
    ushort* qkvb    = (ushort*)alloc((size_t)S_LEN * 2304 * 2);
    ushort* ctxb    = (ushort*)alloc(SH * 2);
    ushort* ffhb    = (ushort*)alloc((size_t)S_LEN * FF * 2);
    ushort* wt_qkvo = (ushort*)alloc((size_t)8 * WW * 2);
    ushort* wt_i    = (ushort*)alloc((size_t)2 * WI * 2);
    ushort* wt_o2   = (ushort*)alloc((size_t)2 * WI * 2);

    float* out = (float*)d_out;
    float* icd_logits = out + 1;
    float* cpt_logits = out + 1 + N_ICD;

    trans_kernel<<<dim3(HID/32, HID/32, 2), 256, 0, stream>>>(Wq,  wt_qkvo + 0*WW, HID, HID, WW, 4*WW);
    trans_kernel<<<dim3(HID/32, HID/32, 2), 256, 0, stream>>>(Wk,  wt_qkvo + 1*WW, HID, HID, WW, 4*WW);
    trans_kernel<<<dim3(HID/32, HID/32, 2), 256, 0, stream>>>(Wv,  wt_qkvo + 2*WW, HID, HID, WW, 4*WW);
    trans_kernel<<<dim3(HID/32, HID/32, 2), 256, 0, stream>>>(Wo,  wt_qkvo + 3*WW, HID, HID, WW, 4*WW);
    trans_kernel<<<dim3(FF/32,  HID/32, 2), 256, 0, stream>>>(Wi,  wt_i,  HID, FF, WI, WI);
    trans_kernel<<<dim3(HID/32, FF/32,  2), 256, 0, stream>>>(Wo2, wt_o2, FF, HID, WI, WI);

    embed_ln_kernel<<<S_LEN, 256, 0, stream>>>(ids, we, pe, els, elb, x, xb);

    for (int l = 0; l < NLAYER; l++) {
        const ushort* wt_qkv_l = wt_qkvo + (size_t)l * 4 * WW;
        const ushort* wt_o_l   = wt_qkvo + (size_t)l * 4 * WW + 3 * WW;
        const ushort* wt_i_l   = wt_i  + (size_t)l * WI;
        const ushort* wt_o2_l  = wt_o2 + (size_t)l * WI;

        pack_bias_kernel<<<3, 256, 0, stream>>>(bq + l*HID, bk + l*HID, bv + l*HID, bqkv);
        gemm_mfma_kernel<128,0,0,1><<<dim3(2304/128, S_LEN/128), 256, 0, stream>>>(
            xb, wt_qkv_l, bqkv, nullptr, qkvb, S_LEN, 2304, HID);

        band_attn_kernel<<<dim3(S_LEN/QB, NHEAD), 256, 0, stream>>>(qkvb, mask, ctxb);

        gemm_mfma_kernel<64,0,1,0><<<dim3(HID/64, S_LEN/128), 256, 0, stream>>>(
            ctxb, wt_o_l, bo + l*HID, tmp, nullptr, S_LEN, HID, HID);
        residual_ln_kernel<<<S_LEN, 256, 0, stream>>>(x, tmp, l1s + l*HID, l1b + l*HID, xb);

        gemm_mfma_kernel<128,1,0,1><<<dim3(FF/128, S_LEN/128), 256, 0, stream>>>(
            xb, wt_i_l, bi + l*FF, nullptr, ffhb, S_LEN, FF, HID);
        gemm_mfma_kernel<64,0,1,0><<<dim3(HID/64, S_LEN/128), 256, 0, stream>>>(
            ffhb, wt_o2_l, bo2 + l*HID, tmp, nullptr, S_LEN, HID, FF);
        residual_ln_kernel<<<S_LEN, 256, 0, stream>>>(x, tmp, l2s + l*HID, l2b + l*HID, xb);
    }

    head_partial_kernel<<<dim3((N_ICD + 63) / 64, 8), 256, 0, stream>>>(x, W_icd, hp_icd, N_ICD);
    head_partial_kernel<<<dim3((N_CPT + 63) / 64, 8), 256, 0, stream>>>(x, W_cpt, hp_cpt, N_CPT);
    head_partial_kernel<<<dim3(1, 8), 256, 0, stream>>>(x, W_ch, hp_ch, N_CH);

    head_focal_kernel<<<16, 256, 0, stream>>>(hp_icd, b_icd, icd_lab, N_ICD, icd_logits, fpart);
    head_focal_kernel<<<16, 256, 0, stream>>>(hp_cpt, b_cpt, cpt_lab, N_CPT, cpt_logits, fpart + 16);
    head_focal_kernel<<<1, 256, 0, stream>>>(hp_ch, b_ch, ch_lab, N_CH, chl, fpart + 32);

    final_loss_kernel<<<1, 1, 0, stream>>>(fpart, out);
}

// Round 7
// 462.957 us; speedup vs baseline: 12.9371x; 1.0697x over previous
//
#include <hip/hip_runtime.h>
#include <hip/hip_bf16.h>
#include <math.h>

#define S_LEN 4096
#define HID 768
#define NHEAD 12
#define NLAYER 2
#define WIN 256
#define FF 3072
#define N_ICD 8000
#define N_CPT 5000
#define N_CH 22

typedef short s16x8 __attribute__((ext_vector_type(8)));
typedef float fx4 __attribute__((ext_vector_type(4)));

__device__ __forceinline__ ushort f2bf(float f) {
    union { float f; uint u; } c; c.f = f;
    uint u = c.u + 0x7fffu + ((c.u >> 16) & 1u);
    return (ushort)(u >> 16);
}

// async global->LDS, 16B per lane; l must be the wave-uniform base (HW adds lane*16)
__device__ __forceinline__ void gld_lds16(const ushort* g, ushort* l) {
    __builtin_amdgcn_global_load_lds(
        (const __attribute__((address_space(1))) unsigned int*)g,
        (__attribute__((address_space(3))) unsigned int*)l, 16, 0, 0);
}

// bijective XCD-chunk swizzle (m204): maps linear bid so each XCD gets a
// contiguous chunk of the grid.
__device__ __forceinline__ int xcd_swizzle(int bid, int nwg) {
    int q = nwg >> 3, r = nwg & 7;
    int xcd = bid & 7, idx = bid >> 3;
    return (xcd < r ? xcd * (q + 1) : r * (q + 1) + (xcd - r) * q) + idx;
}

// ---------------- block reduce (deterministic) ----------------
__device__ __forceinline__ float breduce(float v, volatile float* red) {
    int t = threadIdx.x;
    #pragma unroll
    for (int o = 32; o > 0; o >>= 1) v += __shfl_down(v, o, 64);
    __syncthreads();
    if ((t & 63) == 0) red[t >> 6] = v;
    __syncthreads();
    return red[0] + red[1] + red[2] + red[3];
}

// ---------------- fused QKVO weight transpose (both layers) ----------------
__global__ __launch_bounds__(256) void trans_qkvo_kernel(
    const float* __restrict__ Wq, const float* __restrict__ Wk,
    const float* __restrict__ Wv, const float* __restrict__ Wo_,
    ushort* __restrict__ out) {
    __shared__ float T[32][33];
    int z = blockIdx.z;            // 0..7 = weight*2 + layer
    int wsel = z >> 1, l = z & 1;
    const size_t WW = (size_t)HID * HID;
    const float* in = (wsel == 0 ? Wq : wsel == 1 ? Wk : wsel == 2 ? Wv : Wo_) + (size_t)l * WW;
    ushort* o = out + ((size_t)l * 4 + wsel) * WW;
    int tx = threadIdx.x & 31, ty = threadIdx.x >> 5;
    int n0 = blockIdx.x * 32, k0 = blockIdx.y * 32;
    #pragma unroll
    for (int i = 0; i < 32; i += 8)
        T[ty + i][tx] = in[(size_t)(k0 + ty + i) * HID + n0 + tx];
    __syncthreads();
    #pragma unroll
    for (int i = 0; i < 32; i += 8)
        o[(size_t)(n0 + ty + i) * HID + k0 + tx] = f2bf(T[tx][ty + i]);
}

// ---------------- generic transpose for FFN weights ----------------
__global__ __launch_bounds__(256) void trans_kernel(
    const float* __restrict__ in, ushort* __restrict__ out,
    int K, int N, size_t in_z, size_t out_z) {
    __shared__ float T[32][33];
    in += blockIdx.z * in_z; out += blockIdx.z * out_z;
    int tx = threadIdx.x & 31, ty = threadIdx.x >> 5;
    int n0 = blockIdx.x * 32, k0 = blockIdx.y * 32;
    #pragma unroll
    for (int i = 0; i < 32; i += 8)
        T[ty + i][tx] = in[(size_t)(k0 + ty + i) * N + n0 + tx];
    __syncthreads();
    #pragma unroll
    for (int i = 0; i < 32; i += 8)
        out[(size_t)(n0 + ty + i) * K + k0 + tx] = f2bf(T[tx][ty + i]);
}

// ---------------- pack QKV bias (both layers) ----------------
__global__ __launch_bounds__(256) void pack_bias_kernel(
    const float* __restrict__ bq, const float* __restrict__ bk,
    const float* __restrict__ bv, float* __restrict__ dst) {
    int l = blockIdx.y;
    int i = blockIdx.x * 256 + threadIdx.x;
    if (i < HID) {
        dst[l * 2304 + i]           = bq[l * HID + i];
        dst[l * 2304 + HID + i]     = bk[l * HID + i];
        dst[l * 2304 + 2 * HID + i] = bv[l * HID + i];
    }
}

// ---------------- embedding + LN ----------------
__global__ __launch_bounds__(256) void embed_ln_kernel(
    const int* __restrict__ ids, const float* __restrict__ we,
    const float* __restrict__ pe, const float* __restrict__ ls,
    const float* __restrict__ lb, float* __restrict__ x, ushort* __restrict__ xb) {
    __shared__ float red[4];
    int srow = blockIdx.x, t = threadIdx.x;
    int id = ids[srow];
    float v[3];
    #pragma unroll
    for (int i = 0; i < 3; i++) {
        int hh = i * 256 + t;
        v[i] = we[(size_t)id * HID + hh] + pe[srow * HID + hh];
    }
    float mean = breduce(v[0] + v[1] + v[2], red) * (1.f / HID);
    __syncthreads();
    float sq = 0.f;
    #pragma unroll
    for (int i = 0; i < 3; i++) { float d = v[i] - mean; sq += d * d; }
    float var = breduce(sq, red) * (1.f / HID);
    float inv = rsqrtf(var + 1e-5f);
    #pragma unroll
    for (int i = 0; i < 3; i++) {
        int hh = i * 256 + t;
        float o = (v[i] - mean) * inv * ls[hh] + lb[hh];
        x[srow * HID + hh] = o;
        xb[srow * HID + hh] = f2bf(o);
    }
}

// ---------------- residual + LN ----------------
__global__ __launch_bounds__(256) void residual_ln_kernel(
    float* __restrict__ x, const float* __restrict__ y,
    const float* __restrict__ ls, const float* __restrict__ lb,
    ushort* __restrict__ xb) {
    __shared__ float red[4];
    int srow = blockIdx.x, t = threadIdx.x;
    float v[3];
    #pragma unroll
    for (int i = 0; i < 3; i++) {
        int hh = i * 256 + t;
        v[i] = x[srow * HID + hh] + y[srow * HID + hh];
    }
    float mean = breduce(v[0] + v[1] + v[2], red) * (1.f / HID);
    __syncthreads();
    float sq = 0.f;
    #pragma unroll
    for (int i = 0; i < 3; i++) { float d = v[i] - mean; sq += d * d; }
    float var = breduce(sq, red) * (1.f / HID);
    float inv = rsqrtf(var + 1e-5f);
    #pragma unroll
    for (int i = 0; i < 3; i++) {
        int hh = i * 256 + t;
        float o = (v[i] - mean) * inv * ls[hh] + lb[hh];
        x[srow * HID + hh] = o;
        xb[srow * HID + hh] = f2bf(o);
    }
}

// ---------------- bf16 MFMA GEMM, global_load_lds staging, BK=64, XCD swizzle ----------------
template<int BN, int ACT, int OUTF32, int OUTBF16>
__global__ __launch_bounds__(256) void gemm_mfma_kernel(
    const ushort* __restrict__ A, const ushort* __restrict__ Bt,
    const float* __restrict__ bias, float* __restrict__ C,
    ushort* __restrict__ Cb, int M, int N, int K) {
    constexpr int MF = (BN == 128) ? 4 : 2;
    constexpr int NF = 4;
    constexpr int NBG = (BN == 128) ? 4 : 2;
    __shared__ ushort As[128 * 64];
    __shared__ ushort Bs[BN * 64];
    int t = threadIdx.x;
    int lane = t & 63, wid = t >> 6;
    int lg = lane >> 4, lm = lane & 15;

    int nx = gridDim.x;
    int nwg = nx * gridDim.y;
    int swz = xcd_swizzle(blockIdx.x + nx * blockIdx.y, nwg);
    int m0 = (swz / nx) * 128, n0 = (swz % nx) * BN;

    int wr = (BN == 128) ? (wid >> 1) * 64 : wid * 32;
    int wc = (BN == 128) ? (wid & 1) * 64 : 0;

    fx4 acc[MF][NF];
    #pragma unroll
    for (int i = 0; i < MF; i++)
        #pragma unroll
        for (int j = 0; j < NF; j++) acc[i][j] = (fx4){0.f, 0.f, 0.f, 0.f};

    int srow = lane >> 3, scol = (lane & 7) * 8;
    const ushort* paw = A + (size_t)(m0 + wid * 32 + srow) * K + scol;
    ushort* law = As + wid * 32 * 64;
    const ushort* pbw = Bt + (size_t)(n0 + wid * 8 * NBG + srow) * K + scol;
    ushort* lbw = Bs + wid * 8 * NBG * 64;

    for (int k0 = 0; k0 < K; k0 += 64) {
        #pragma unroll
        for (int i = 0; i < 4; i++)
            gld_lds16(paw + (size_t)i * 8 * K + k0, law + i * 512);
        #pragma unroll
        for (int i = 0; i < NBG; i++)
            gld_lds16(pbw + (size_t)i * 8 * K + k0, lbw + i * 512);
        __syncthreads();
        #pragma unroll
        for (int ks = 0; ks < 2; ks++) {
            s16x8 a[MF], b[NF];
            #pragma unroll
            for (int f = 0; f < MF; f++)
                a[f] = *(const s16x8*)&As[(wr + f * 16 + lm) * 64 + ks * 32 + lg * 8];
            #pragma unroll
            for (int f = 0; f < NF; f++)
                b[f] = *(const s16x8*)&Bs[(wc + f * 16 + lm) * 64 + ks * 32 + lg * 8];
            #pragma unroll
            for (int i = 0; i < MF; i++)
                #pragma unroll
                for (int j = 0; j < NF; j++)
                    acc[i][j] = __builtin_amdgcn_mfma_f32_16x16x32_bf16(a[i], b[j], acc[i][j], 0, 0, 0);
        }
        __syncthreads();
    }
    int crow = lg * 4, ccol = lm;
    #pragma unroll
    for (int i = 0; i < MF; i++) {
        #pragma unroll
        for (int j = 0; j < NF; j++) {
            int col = n0 + wc + j * 16 + ccol;
            float bv_ = bias[col];
            #pragma unroll
            for (int r = 0; r < 4; r++) {
                int row = m0 + wr + i * 16 + crow + r;
                float val = acc[i][j][r] + bv_;
                if (ACT) {
                    float tt = 0.7978845608028654f * (val + 0.044715f * val * val * val);
                    val = val * (1.f / (1.f + __expf(-2.f * tt)));
                }
                if (OUTF32) C[(size_t)row * N + col] = val;
                if (OUTBF16) Cb[(size_t)row * N + col] = f2bf(val);
            }
        }
    }
}

// ---------------- MFMA flash band attention: dbuf + async stage + Q-hoist + defer-max ----------------
#define QB 64
#define KTW 64
#define NKT 9
__global__ __launch_bounds__(256) void band_attn_kernel(
    const ushort* __restrict__ qkv, const float* __restrict__ mask,
    ushort* __restrict__ ctxb) {
    // LDS: K0 V0 K1 V1 (each [64][72]); Q staged in K1's slot during prologue.
    __shared__ ushort KV[4 * 64 * 72];
    __shared__ ushort Ps[4 * 16 * 72];
    __shared__ float  Ms[NKT * KTW];
    ushort* K0 = KV;
    ushort* V0 = KV + 64 * 72;
    ushort* K1 = KV + 2 * 64 * 72;
    ushort* V1 = KV + 3 * 64 * 72;
    ushort* Qs = K1;

    // XCD swizzle: 768 blocks -> 96-block chunks (consecutive q of one head per XCD)
    int bid = blockIdx.x + gridDim.x * blockIdx.y;
    int swz = (bid & 7) * 96 + (bid >> 3);
    int qblk = swz & 63, h = swz >> 6;

    int qbase = qblk * QB;
    int kbase = qbase - WIN;
    int t = threadIdx.x;
    int w = t >> 6, lane = t & 63;
    int lg = lane >> 4, lm = lane & 15;

    const ushort* qP = qkv + h * 64;
    const ushort* kP = qkv + HID + h * 64;
    const ushort* vP = qkv + 2 * HID + h * 64;

    // ---- prologue ----
    {   // stage Q into Qs(=K1)
        int r = t >> 2, c = (t & 3) * 16;
        const ushort* src = qP + (size_t)(qbase + r) * 2304 + c;
        *(uint4*)&Qs[r * 72 + c]     = *(const uint4*)src;
        *(uint4*)&Qs[r * 72 + c + 8] = *(const uint4*)(src + 8);
    }
    for (int i = t; i < NKT * KTW; i += 256) {
        int kp = kbase + i;
        Ms[i] = (kp >= 0 && kp < S_LEN && mask[kp] > 0.5f) ? 1.f : 0.f;
    }
    int krow = t >> 2, kcol = (t & 3) * 16;   // K staging coords
    int vkey = t & 63, vd0 = (t >> 6) * 16;   // V staging coords
    uint4 kr0, kr1, vr0, vr1;
    {   // issue tile-0 loads
        int kp = kbase + krow;
        kr0 = (uint4){0u,0u,0u,0u}; kr1 = kr0;
        if (kp >= 0 && kp < S_LEN) {
            const ushort* ks = kP + (size_t)kp * 2304 + kcol;
            kr0 = *(const uint4*)ks; kr1 = *(const uint4*)(ks + 8);
        }
        int vp = kbase + vkey;
        vr0 = (uint4){0u,0u,0u,0u}; vr1 = vr0;
        if (vp >= 0 && vp < S_LEN) {
            const ushort* vs = vP + (size_t)vp * 2304 + vd0;
            vr0 = *(const uint4*)vs; vr1 = *(const uint4*)(vs + 8);
        }
    }
    __syncthreads();
    // Q fragments -> registers (loop-invariant)
    s16x8 aq0 = *(const s16x8*)&Qs[(w * 16 + lm) * 72 + lg * 8];
    s16x8 aq1 = *(const s16x8*)&Qs[(w * 16 + lm) * 72 + lg * 8 + 32];
    // write tile 0 into buf0
    *(uint4*)&K0[krow * 72 + kcol]     = kr0;
    *(uint4*)&K0[krow * 72 + kcol + 8] = kr1;
    {
        union { uint4 u; ushort s[8]; } a, b;
        a.u = vr0; b.u = vr1;
        #pragma unroll
        for (int j = 0; j < 8; j++) V0[(vd0 + j) * 72 + vkey] = a.s[j];
        #pragma unroll
        for (int j = 0; j < 8; j++) V0[(vd0 + 8 + j) * 72 + vkey] = b.s[j];
    }
    __syncthreads();

    float mrun[4], lsum[4];
    #pragma unroll
    for (int r = 0; r < 4; r++) { mrun[r] = -1e30f; lsum[r] = 0.f; }
    fx4 accO[4];
    #pragma unroll
    for (int rt = 0; rt < 4; rt++) accO[rt] = (fx4){0.f, 0.f, 0.f, 0.f};

    int q0 = qbase + w * 16;
    const float scale = 0.125f;
    const fx4 zf = (fx4){0.f, 0.f, 0.f, 0.f};

    for (int kt = 0; kt < NKT; kt++) {
        bool pre = (kt + 1 < NKT);
        if (pre) {   // issue next-tile loads (latency hides under compute)
            int kp = kbase + (kt + 1) * KTW + krow;
            kr0 = (uint4){0u,0u,0u,0u}; kr1 = kr0;
            if (kp >= 0 && kp < S_LEN) {
                const ushort* ks = kP + (size_t)kp * 2304 + kcol;
                kr0 = *(const uint4*)ks; kr1 = *(const uint4*)(ks + 8);
            }
            int vp = kbase + (kt + 1) * KTW + vkey;
            vr0 = (uint4){0u,0u,0u,0u}; vr1 = vr0;
            if (vp >= 0 && vp < S_LEN) {
                const ushort* vs = vP + (size_t)vp * 2304 + vd0;
                vr0 = *(const uint4*)vs; vr1 = *(const uint4*)(vs + 8);
            }
        }
        const ushort* Kc = (kt & 1) ? K1 : K0;
        const ushort* Vc = (kt & 1) ? V1 : V0;
        ushort* Kn = (kt & 1) ? K0 : K1;
        ushort* Vn = (kt & 1) ? V0 : V1;

        // QK^T
        fx4 sc[4];
        #pragma unroll
        for (int j = 0; j < 4; j++) {
            s16x8 b0 = *(const s16x8*)&Kc[(j * 16 + lm) * 72 + lg * 8];
            s16x8 b1 = *(const s16x8*)&Kc[(j * 16 + lm) * 72 + lg * 8 + 32];
            sc[j] = __builtin_amdgcn_mfma_f32_16x16x32_bf16(aq0, b0, zf, 0, 0, 0);
            sc[j] = __builtin_amdgcn_mfma_f32_16x16x32_bf16(aq1, b1, sc[j], 0, 0, 0);
        }
        // mask + scale + row max
        float tm[4];
        #pragma unroll
        for (int r = 0; r < 4; r++) {
            int qp = q0 + lg * 4 + r;
            tm[r] = -1e30f;
            #pragma unroll
            for (int j = 0; j < 4; j++) {
                int krel = kt * KTW + j * 16 + lm;
                int dd = kbase + krel - qp;
                bool ok = (dd >= -WIN) && (dd <= WIN) && (Ms[krel] != 0.f);
                sc[j][r] = ok ? sc[j][r] * scale : -1e30f;
                tm[r] = fmaxf(tm[r], sc[j][r]);
            }
        }
        #pragma unroll
        for (int r = 0; r < 4; r++)
            #pragma unroll
            for (int o = 1; o < 16; o <<= 1)
                tm[r] = fmaxf(tm[r], __shfl_xor(tm[r], o, 16));

        // defer-max: only rescale when a row max grew beyond threshold
        bool grow = (tm[0] > mrun[0] + 8.f) || (tm[1] > mrun[1] + 8.f) ||
                    (tm[2] > mrun[2] + 8.f) || (tm[3] > mrun[3] + 8.f);
        int anyg = __any((int)grow);
        float corr[4] = {1.f, 1.f, 1.f, 1.f};
        if (anyg) {
            #pragma unroll
            for (int r = 0; r < 4; r++) {
                float nm = fmaxf(mrun[r], tm[r]);
                corr[r] = __expf(mrun[r] - nm);
                mrun[r] = nm;
            }
        }
        #pragma unroll
        for (int r = 0; r < 4; r++) {
            float p[4], rs = 0.f;
            #pragma unroll
            for (int j = 0; j < 4; j++) {
                p[j] = __expf(sc[j][r] - mrun[r]);
                if (sc[j][r] < -1e29f) p[j] = 0.f;
                rs += p[j];
            }
            #pragma unroll
            for (int o = 1; o < 16; o <<= 1) rs += __shfl_xor(rs, o, 16);
            lsum[r] = lsum[r] * corr[r] + rs;
            #pragma unroll
            for (int j = 0; j < 4; j++)
                Ps[(w * 16 + lg * 4 + r) * 72 + j * 16 + lm] = f2bf(p[j]);
        }
        if (anyg) {   // transfer corr to O-layout + rescale accumulator
            float c0 = __shfl(corr[0], (lm >> 2) * 16);
            float c1 = __shfl(corr[1], (lm >> 2) * 16);
            float c2 = __shfl(corr[2], (lm >> 2) * 16);
            float c3 = __shfl(corr[3], (lm >> 2) * 16);
            float cw = (lm & 2) ? ((lm & 1) ? c3 : c2) : ((lm & 1) ? c1 : c0);
            #pragma unroll
            for (int rt = 0; rt < 4; rt++) {
                accO[rt][0] *= cw; accO[rt][1] *= cw;
                accO[rt][2] *= cw; accO[rt][3] *= cw;
            }
        }
        asm volatile("s_waitcnt lgkmcnt(0)" ::: "memory");
        // PV: O^T[dim][query]
        s16x8 bp0 = *(const s16x8*)&Ps[(w * 16 + lm) * 72 + lg * 8];
        s16x8 bp1 = *(const s16x8*)&Ps[(w * 16 + lm) * 72 + lg * 8 + 32];
        #pragma unroll
        for (int rt = 0; rt < 4; rt++) {
            s16x8 av0 = *(const s16x8*)&Vc[(rt * 16 + lm) * 72 + lg * 8];
            s16x8 av1 = *(const s16x8*)&Vc[(rt * 16 + lm) * 72 + lg * 8 + 32];
            accO[rt] = __builtin_amdgcn_mfma_f32_16x16x32_bf16(av0, bp0, accO[rt], 0, 0, 0);
            accO[rt] = __builtin_amdgcn_mfma_f32_16x16x32_bf16(av1, bp1, accO[rt], 0, 0, 0);
        }

        if (pre) {   // write next tile into the other buffer, single barrier
            *(uint4*)&Kn[krow * 72 + kcol]     = kr0;
            *(uint4*)&Kn[krow * 72 + kcol + 8] = kr1;
            union { uint4 u; ushort s[8]; } a, b;
            a.u = vr0; b.u = vr1;
            #pragma unroll
            for (int j = 0; j < 8; j++) Vn[(vd0 + j) * 72 + vkey] = a.s[j];
            #pragma unroll
            for (int j = 0; j < 8; j++) Vn[(vd0 + 8 + j) * 72 + vkey] = b.s[j];
            __syncthreads();
        }
    }

    float l0 = __shfl(lsum[0], (lm >> 2) * 16);
    float l1 = __shfl(lsum[1], (lm >> 2) * 16);
    float l2 = __shfl(lsum[2], (lm >> 2) * 16);
    float l3 = __shfl(lsum[3], (lm >> 2) * 16);
    float lw = (lm & 2) ? ((lm & 1) ? l3 : l2) : ((lm & 1) ? l1 : l0);
    float inv = 1.f / lw;
    int q = q0 + lm;
    #pragma unroll
    for (int rt = 0; rt < 4; rt++) {
        int dbase = rt * 16 + lg * 4;
        uint2 wv;
        wv.x = (uint)f2bf(accO[rt][0] * inv) | ((uint)f2bf(accO[rt][1] * inv) << 16);
        wv.y = (uint)f2bf(accO[rt][2] * inv) | ((uint)f2bf(accO[rt][3] * inv) << 16);
        *(uint2*)(ctxb + (size_t)q * HID + h * 64 + dbase) = wv;
    }
}

// ---------------- fused heads: split-K partial GEMV (3 heads in one launch) ----------------
__global__ __launch_bounds__(256) void heads_partial_kernel(
    const float* __restrict__ x0,
    const float* __restrict__ W0, const float* __restrict__ W1, const float* __restrict__ W2,
    float* __restrict__ p0, float* __restrict__ p1, float* __restrict__ p2) {
    int which = blockIdx.z;
    const float* Wt = which == 0 ? W0 : which == 1 ? W1 : W2;
    float* part     = which == 0 ? p0 : which == 1 ? p1 : p2;
    int N           = which == 0 ? N_ICD : which == 1 ? N_CPT : N_CH;
    if (blockIdx.x * 64 >= N) return;
    __shared__ float red[256];
    int t = threadIdx.x;
    int nn = blockIdx.x * 64 + (t & 63);
    int ks = t >> 6;
    int kc = blockIdx.y;
    int h0 = kc * 96 + ks * 24;
    float s = 0.f;
    if (nn < N) {
        #pragma unroll
        for (int kk = 0; kk < 24; kk++)
            s += x0[h0 + kk] * Wt[(size_t)(h0 + kk) * N + nn];
    }
    red[t] = s;
    __syncthreads();
    if (t < 64 && nn < N)
        part[(size_t)kc * N + nn] = (red[t] + red[t + 64]) + (red[t + 128] + red[t + 192]);
}

// ---------------- fused combine+focal (33 blocks: 16 icd, 16 cpt, 1 ch) ----------------
__global__ __launch_bounds__(256) void heads_focal_kernel(
    const float* __restrict__ p0, const float* __restrict__ p1, const float* __restrict__ p2,
    const float* __restrict__ b0, const float* __restrict__ b1, const float* __restrict__ b2,
    const float* __restrict__ t0, const float* __restrict__ t1, const float* __restrict__ t2,
    float* __restrict__ lg0, float* __restrict__ lg1, float* __restrict__ lg2,
    float* __restrict__ fpart) {
    int b = blockIdx.x;
    int which = b < 16 ? 0 : (b < 32 ? 1 : 2);
    int bi = which == 0 ? b : (which == 1 ? b - 16 : 0);
    int nb = which == 2 ? 1 : 16;
    const float* part  = which == 0 ? p0 : which == 1 ? p1 : p2;
    const float* bias  = which == 0 ? b0 : which == 1 ? b1 : b2;
    const float* tgt   = which == 0 ? t0 : which == 1 ? t1 : t2;
    float* logits      = which == 0 ? lg0 : which == 1 ? lg1 : lg2;
    int N              = which == 0 ? N_ICD : which == 1 ? N_CPT : N_CH;
    __shared__ float red[256];
    int t = threadIdx.x;
    float s = 0.f;
    for (int i = bi * 256 + t; i < N; i += nb * 256) {
        float l = bias[i];
        #pragma unroll
        for (int kc = 0; kc < 8; kc++) l += part[(size_t)kc * N + i];
        logits[i] = l;
        float y = tgt[i];
        float bce = fmaxf(l, 0.f) - l * y + log1pf(expf(-fabsf(l)));
        float pt = expf(-bce);
        float om = 1.f - pt;
        s += om * om * bce;
    }
    red[t] = s;
    __syncthreads();
    for (int o = 128; o > 0; o >>= 1) {
        if (t < o) red[t] += red[t + o];
        __syncthreads();
    }
    if (t == 0) fpart[b] = red[0];
}

__global__ void final_loss_kernel(const float* __restrict__ parts, float* __restrict__ out) {
    if (threadIdx.x == 0 && blockIdx.x == 0) {
        float a = 0.f, b = 0.f, c;
        for (int i = 0; i < 16; i++) a += parts[i];
        for (int i = 0; i < 16; i++) b += parts[16 + i];
        c = parts[32];
        out[0] = a / (float)N_ICD + b / (float)N_CPT + c / (float)N_CH;
    }
}

// ---------------- launch ----------------
extern "C" void kernel_launch(void* const* d_in, const int* in_sizes, int n_in,
                              void* d_out, int out_size, void* d_ws, size_t ws_size,
                              hipStream_t stream) {
    const int*   ids      = (const int*)d_in[0];
    const float* mask     = (const float*)d_in[1];
    const float* icd_lab  = (const float*)d_in[2];
    const float* cpt_lab  = (const float*)d_in[3];
    const float* ch_lab   = (const float*)d_in[4];
    const float* we       = (const float*)d_in[5];
    const float* pe       = (const float*)d_in[6];
    const float* els      = (const float*)d_in[7];
    const float* elb      = (const float*)d_in[8];
    const float* Wq       = (const float*)d_in[9];
    const float* bq       = (const float*)d_in[10];
    const float* Wk       = (const float*)d_in[11];
    const float* bk       = (const float*)d_in[12];
    const float* Wv       = (const float*)d_in[13];
    const float* bv       = (const float*)d_in[14];
    const float* Wo       = (const float*)d_in[15];
    const float* bo       = (const float*)d_in[16];
    const float* l1s      = (const float*)d_in[17];
    const float* l1b      = (const float*)d_in[18];
    const float* Wi       = (const float*)d_in[19];
    const float* bi       = (const float*)d_in[20];
    const float* Wo2      = (const float*)d_in[21];
    const float* bo2      = (const float*)d_in[22];
    const float* l2s      = (const float*)d_in[23];
    const float* l2b      = (const float*)d_in[24];
    const float* W_icd    = (const float*)d_in[25];
    const float* b_icd    = (const float*)d_in[26];
    const float* W_cpt    = (const float*)d_in[27];
    const float* b_cpt    = (const float*)d_in[28];
    const float* W_ch     = (const float*)d_in[29];
    const float* b_ch     = (const float*)d_in[30];

    const size_t SH = (size_t)S_LEN * HID;
    const size_t WW = (size_t)HID * HID;
    const size_t WI = (size_t)HID * FF;

    char* base = (char*)d_ws;
    size_t off = 0;
    auto alloc = [&](size_t bytes) { void* p = base + off; off += (bytes + 255) & ~(size_t)255; return p; };

    float* x     = (float*)alloc(SH * 4);
    float* tmp   = (float*)alloc(SH * 4);
    float* bqkv  = (float*)alloc(2 * 2304 * 4);
    float* chl   = (float*)alloc(32 * 4);
    float* fpart = (float*)alloc(64 * 4);
    float* hp_icd = (float*)alloc((size_t)8 * N_ICD * 4);
    float* hp_cpt = (float*)alloc((size_t)8 * N_CPT * 4);
    float* hp_ch  = (float*)alloc((size_t)8 * 32 * 4);
    ushort* xb      = (ushort*)alloc(SH * 2);
    ushort* qkvb    = (ushort*)alloc((size_t)S_LEN * 2304 * 2);
    ushort* ctxb    = (ushort*)alloc(SH * 2);
    ushort* ffhb    = (ushort*)alloc((size_t)S_LEN * FF * 2);
    ushort* wt_qkvo = (ushort*)alloc((size_t)8 * WW * 2);
    ushort* wt_i    = (ushort*)alloc((size_t)2 * WI * 2);
    ushort* wt_o2   = (ushort*)alloc((size_t)2 * WI * 2);

    float* out = (float*)d_out;
    float* icd_logits = out + 1;
    float* cpt_logits = out + 1 + N_ICD;

    trans_qkvo_kernel<<<dim3(HID/32, HID/32, 8), 256, 0, stream>>>(Wq, Wk, Wv, Wo, wt_qkvo);
    trans_kernel<<<dim3(FF/32,  HID/32, 2), 256, 0, stream>>>(Wi,  wt_i,  HID, FF, WI, WI);
    trans_kernel<<<dim3(HID/32, FF/32,  2), 256, 0, stream>>>(Wo2, wt_o2, FF, HID, WI, WI);
    pack_bias_kernel<<<dim3(3, 2), 256, 0, stream>>>(bq, bk, bv, bqkv);

    embed_ln_kernel<<<S_LEN, 256, 0, stream>>>(ids, we, pe, els, elb, x, xb);

    for (int l = 0; l < NLAYER; l++) {
        const ushort* wt_qkv_l = wt_qkvo + (size_t)l * 4 * WW;
        const ushort* wt_o_l   = wt_qkvo + (size_t)l * 4 * WW + 3 * WW;
        const ushort* wt_i_l   = wt_i  + (size_t)l * WI;
        const ushort* wt_o2_l  = wt_o2 + (size_t)l * WI;

        gemm_mfma_kernel<128,0,0,1><<<dim3(2304/128, S_LEN/128), 256, 0, stream>>>(
            xb, wt_qkv_l, bqkv + l * 2304, nullptr, qkvb, S_LEN, 2304, HID);

        band_attn_kernel<<<dim3(S_LEN/QB, NHEAD), 256, 0, stream>>>(qkvb, mask, ctxb);

        gemm_mfma_kernel<64,0,1,0><<<dim3(HID/64, S_LEN/128), 256, 0, stream>>>(
            ctxb, wt_o_l, bo + l*HID, tmp, nullptr, S_LEN, HID, HID);
        residual_ln_kernel<<<S_LEN, 256, 0, stream>>>(x, tmp, l1s + l*HID, l1b + l*HID, xb);

        gemm_mfma_kernel<128,1,0,1><<<dim3(FF/128, S_LEN/128), 256, 0, stream>>>(
            xb, wt_i_l, bi + l*FF, nullptr, ffhb, S_LEN, FF, HID);
        gemm_mfma_kernel<64,0,1,0><<<dim3(HID/64, S_LEN/128), 256, 0, stream>>>(
            ffhb, wt_o2_l, bo2 + l*HID, tmp, nullptr, S_LEN, HID, FF);
        residual_ln_kernel<<<S_LEN, 256, 0, stream>>>(x, tmp, l2s + l*HID, l2b + l*HID, xb);
    }

    heads_partial_kernel<<<dim3((N_ICD + 63) / 64, 8, 3), 256, 0, stream>>>(
        x, W_icd, W_cpt, W_ch, hp_icd, hp_cpt, hp_ch);
    heads_focal_kernel<<<33, 256, 0, stream>>>(
        hp_icd, hp_cpt, hp_ch, b_icd, b_cpt, b_ch, icd_lab, cpt_lab, ch_lab,
        icd_logits, cpt_logits, chl, fpart);
    final_loss_kernel<<<1, 1, 0, stream>>>(fpart, out);
}

// Round 8
// 443.529 us; speedup vs baseline: 13.5038x; 1.0438x over previous
//
#include <hip/hip_runtime.h>
#include <hip/hip_bf16.h>
#include <math.h>

#define S_LEN 4096
#define HID 768
#define NHEAD 12
#define NLAYER 2
#define WIN 256
#define FF 3072
#define N_ICD 8000
#define N_CPT 5000
#define N_CH 22

typedef short s16x8 __attribute__((ext_vector_type(8)));
typedef float fx4 __attribute__((ext_vector_type(4)));

__device__ __forceinline__ ushort f2bf(float f) {
    union { float f; uint u; } c; c.f = f;
    uint u = c.u + 0x7fffu + ((c.u >> 16) & 1u);
    return (ushort)(u >> 16);
}

// async global->LDS, 16B per lane; l must be the wave-uniform base (HW adds lane*16)
__device__ __forceinline__ void gld_lds16(const ushort* g, ushort* l) {
    __builtin_amdgcn_global_load_lds(
        (const __attribute__((address_space(1))) unsigned int*)g,
        (__attribute__((address_space(3))) unsigned int*)l, 16, 0, 0);
}

// bijective XCD-chunk swizzle (m204)
__device__ __forceinline__ int xcd_swizzle(int bid, int nwg) {
    int q = nwg >> 3, r = nwg & 7;
    int xcd = bid & 7, idx = bid >> 3;
    return (xcd < r ? xcd * (q + 1) : r * (q + 1) + (xcd - r) * q) + idx;
}

// ---------------- block reduce (deterministic) ----------------
__device__ __forceinline__ float breduce(float v, volatile float* red) {
    int t = threadIdx.x;
    #pragma unroll
    for (int o = 32; o > 0; o >>= 1) v += __shfl_down(v, o, 64);
    __syncthreads();
    if ((t & 63) == 0) red[t >> 6] = v;
    __syncthreads();
    return red[0] + red[1] + red[2] + red[3];
}

// ---------------- unified prep: all weight transposes + bias pack ----------------
// grid (96, 24, 13)
__global__ __launch_bounds__(256) void prep_kernel(
    const float* __restrict__ Wq, const float* __restrict__ Wk,
    const float* __restrict__ Wv, const float* __restrict__ Wo_,
    const float* __restrict__ Wi, const float* __restrict__ Wo2,
    const float* __restrict__ bq, const float* __restrict__ bk,
    const float* __restrict__ bv,
    ushort* __restrict__ wt_qkvo, ushort* __restrict__ wt_i,
    ushort* __restrict__ wt_o2, float* __restrict__ bqkv) {
    const size_t WW = (size_t)HID * HID;
    const size_t WI = (size_t)HID * FF;
    int z = blockIdx.z, bx = blockIdx.x, by = blockIdx.y;
    int t = threadIdx.x;
    if (z == 12) {
        if (by < 2 && bx < 3) {
            int l = by, i = bx * 256 + t;
            if (i < HID) {
                bqkv[l * 2304 + i]           = bq[l * HID + i];
                bqkv[l * 2304 + HID + i]     = bk[l * HID + i];
                bqkv[l * 2304 + 2 * HID + i] = bv[l * HID + i];
            }
        }
        return;
    }
    const float* in; ushort* out; int K, N, n0, k0;
    if (z < 8) {
        if (bx >= 24 || by >= 24) return;
        int wsel = z >> 1, l = z & 1;
        in = (wsel == 0 ? Wq : wsel == 1 ? Wk : wsel == 2 ? Wv : Wo_) + (size_t)l * WW;
        out = wt_qkvo + ((size_t)l * 4 + wsel) * WW;
        K = HID; N = HID; n0 = bx * 32; k0 = by * 32;
    } else if (z < 10) {
        int l = z - 8;
        in = Wi + (size_t)l * WI; out = wt_i + (size_t)l * WI;
        K = HID; N = FF; n0 = bx * 32; k0 = by * 32;
    } else {
        int l = z - 10;
        in = Wo2 + (size_t)l * WI; out = wt_o2 + (size_t)l * WI;
        K = FF; N = HID; n0 = by * 32; k0 = bx * 32;
    }
    __shared__ float T[32][33];
    int tx = t & 31, ty = t >> 5;
    #pragma unroll
    for (int i = 0; i < 32; i += 8)
        T[ty + i][tx] = in[(size_t)(k0 + ty + i) * N + n0 + tx];
    __syncthreads();
    #pragma unroll
    for (int i = 0; i < 32; i += 8)
        out[(size_t)(n0 + ty + i) * K + k0 + tx] = f2bf(T[tx][ty + i]);
}

// ---------------- embedding + LN ----------------
__global__ __launch_bounds__(256) void embed_ln_kernel(
    const int* __restrict__ ids, const float* __restrict__ we,
    const float* __restrict__ pe, const float* __restrict__ ls,
    const float* __restrict__ lb, float* __restrict__ x, ushort* __restrict__ xb) {
    __shared__ float red[4];
    int srow = blockIdx.x, t = threadIdx.x;
    int id = ids[srow];
    float v[3];
    #pragma unroll
    for (int i = 0; i < 3; i++) {
        int hh = i * 256 + t;
        v[i] = we[(size_t)id * HID + hh] + pe[srow * HID + hh];
    }
    float mean = breduce(v[0] + v[1] + v[2], red) * (1.f / HID);
    __syncthreads();
    float sq = 0.f;
    #pragma unroll
    for (int i = 0; i < 3; i++) { float d = v[i] - mean; sq += d * d; }
    float var = breduce(sq, red) * (1.f / HID);
    float inv = rsqrtf(var + 1e-5f);
    #pragma unroll
    for (int i = 0; i < 3; i++) {
        int hh = i * 256 + t;
        float o = (v[i] - mean) * inv * ls[hh] + lb[hh];
        x[srow * HID + hh] = o;
        xb[srow * HID + hh] = f2bf(o);
    }
}

// ---------------- residual + LN ----------------
__global__ __launch_bounds__(256) void residual_ln_kernel(
    float* __restrict__ x, const float* __restrict__ y,
    const float* __restrict__ ls, const float* __restrict__ lb,
    ushort* __restrict__ xb) {
    __shared__ float red[4];
    int srow = blockIdx.x, t = threadIdx.x;
    float v[3];
    #pragma unroll
    for (int i = 0; i < 3; i++) {
        int hh = i * 256 + t;
        v[i] = x[srow * HID + hh] + y[srow * HID + hh];
    }
    float mean = breduce(v[0] + v[1] + v[2], red) * (1.f / HID);
    __syncthreads();
    float sq = 0.f;
    #pragma unroll
    for (int i = 0; i < 3; i++) { float d = v[i] - mean; sq += d * d; }
    float var = breduce(sq, red) * (1.f / HID);
    float inv = rsqrtf(var + 1e-5f);
    #pragma unroll
    for (int i = 0; i < 3; i++) {
        int hh = i * 256 + t;
        float o = (v[i] - mean) * inv * ls[hh] + lb[hh];
        x[srow * HID + hh] = o;
        xb[srow * HID + hh] = f2bf(o);
    }
}

// ---------------- bf16 MFMA GEMM, global_load_lds staging, BK=64, XCD swizzle ----------------
template<int BN, int ACT, int OUTF32, int OUTBF16>
__global__ __launch_bounds__(256) void gemm_mfma_kernel(
    const ushort* __restrict__ A, const ushort* __restrict__ Bt,
    const float* __restrict__ bias, float* __restrict__ C,
    ushort* __restrict__ Cb, int M, int N, int K) {
    constexpr int MF = (BN == 128) ? 4 : 2;
    constexpr int NF = 4;
    constexpr int NBG = (BN == 128) ? 4 : 2;
    __shared__ ushort As[128 * 64];
    __shared__ ushort Bs[BN * 64];
    int t = threadIdx.x;
    int lane = t & 63, wid = t >> 6;
    int lg = lane >> 4, lm = lane & 15;

    int nx = gridDim.x;
    int nwg = nx * gridDim.y;
    int swz = xcd_swizzle(blockIdx.x + nx * blockIdx.y, nwg);
    int m0 = (swz / nx) * 128, n0 = (swz % nx) * BN;

    int wr = (BN == 128) ? (wid >> 1) * 64 : wid * 32;
    int wc = (BN == 128) ? (wid & 1) * 64 : 0;

    fx4 acc[MF][NF];
    #pragma unroll
    for (int i = 0; i < MF; i++)
        #pragma unroll
        for (int j = 0; j < NF; j++) acc[i][j] = (fx4){0.f, 0.f, 0.f, 0.f};

    int srow = lane >> 3, scol = (lane & 7) * 8;
    const ushort* paw = A + (size_t)(m0 + wid * 32 + srow) * K + scol;
    ushort* law = As + wid * 32 * 64;
    const ushort* pbw = Bt + (size_t)(n0 + wid * 8 * NBG + srow) * K + scol;
    ushort* lbw = Bs + wid * 8 * NBG * 64;

    for (int k0 = 0; k0 < K; k0 += 64) {
        #pragma unroll
        for (int i = 0; i < 4; i++)
            gld_lds16(paw + (size_t)i * 8 * K + k0, law + i * 512);
        #pragma unroll
        for (int i = 0; i < NBG; i++)
            gld_lds16(pbw + (size_t)i * 8 * K + k0, lbw + i * 512);
        __syncthreads();
        #pragma unroll
        for (int ks = 0; ks < 2; ks++) {
            s16x8 a[MF], b[NF];
            #pragma unroll
            for (int f = 0; f < MF; f++)
                a[f] = *(const s16x8*)&As[(wr + f * 16 + lm) * 64 + ks * 32 + lg * 8];
            #pragma unroll
            for (int f = 0; f < NF; f++)
                b[f] = *(const s16x8*)&Bs[(wc + f * 16 + lm) * 64 + ks * 32 + lg * 8];
            #pragma unroll
            for (int i = 0; i < MF; i++)
                #pragma unroll
                for (int j = 0; j < NF; j++)
                    acc[i][j] = __builtin_amdgcn_mfma_f32_16x16x32_bf16(a[i], b[j], acc[i][j], 0, 0, 0);
        }
        __syncthreads();
    }
    int crow = lg * 4, ccol = lm;
    #pragma unroll
    for (int i = 0; i < MF; i++) {
        #pragma unroll
        for (int j = 0; j < NF; j++) {
            int col = n0 + wc + j * 16 + ccol;
            float bv_ = bias[col];
            #pragma unroll
            for (int r = 0; r < 4; r++) {
                int row = m0 + wr + i * 16 + crow + r;
                float val = acc[i][j][r] + bv_;
                if (ACT) {
                    float tt = 0.7978845608028654f * (val + 0.044715f * val * val * val);
                    val = val * (1.f / (1.f + __expf(-2.f * tt)));
                }
                if (OUTF32) C[(size_t)row * N + col] = val;
                if (OUTBF16) Cb[(size_t)row * N + col] = f2bf(val);
            }
        }
    }
}

// ---------------- MFMA flash band attention: swapped QK^T, per-query lane state ----------------
#define QB 64
#define KTW 64
#define NKT 9
__global__ __launch_bounds__(256) void band_attn_kernel(
    const ushort* __restrict__ qkv, const float* __restrict__ mask,
    ushort* __restrict__ ctxb) {
    // LDS: K0 V0 K1 V1 (each [64][72]); Q staged in K1's slot during prologue.
    __shared__ ushort KV[4 * 64 * 72];
    __shared__ ushort Ps[4 * 16 * 72];
    __shared__ float  Ms[NKT * KTW];
    ushort* K0 = KV;
    ushort* V0 = KV + 64 * 72;
    ushort* K1 = KV + 2 * 64 * 72;
    ushort* V1 = KV + 3 * 64 * 72;
    ushort* Qs = K1;

    // XCD swizzle: 768 blocks -> 96-block chunks (consecutive q of one head per XCD)
    int bid = blockIdx.x + gridDim.x * blockIdx.y;
    int swz = (bid & 7) * 96 + (bid >> 3);
    int qblk = swz & 63, h = swz >> 6;

    int qbase = qblk * QB;
    int kbase = qbase - WIN;
    int t = threadIdx.x;
    int w = t >> 6, lane = t & 63;
    int lg = lane >> 4, lm = lane & 15;

    // valid tile range: all kp within [kt_lo,kt_hi) tiles are inside [0,S)
    int kt_lo = (qbase < WIN) ? ((WIN - qbase) >> 6) : 0;
    int kt_hi = (S_LEN - qbase + WIN) >> 6;
    if (kt_hi > NKT) kt_hi = NKT;

    const ushort* qP = qkv + h * 64;
    const ushort* kP = qkv + HID + h * 64;
    const ushort* vP = qkv + 2 * HID + h * 64;

    // ---- prologue ----
    {   // stage Q into Qs(=K1)
        int r = t >> 2, c = (t & 3) * 16;
        const ushort* src = qP + (size_t)(qbase + r) * 2304 + c;
        *(uint4*)&Qs[r * 72 + c]     = *(const uint4*)src;
        *(uint4*)&Qs[r * 72 + c + 8] = *(const uint4*)(src + 8);
    }
    for (int i = kt_lo * KTW + t; i < kt_hi * KTW; i += 256)
        Ms[i] = (mask[kbase + i] > 0.5f) ? 1.f : 0.f;

    int krow = t >> 2, kcol = (t & 3) * 16;   // K staging coords
    int vkey = t & 63, vd0 = (t >> 6) * 16;   // V staging coords
    uint4 kr0, kr1, vr0, vr1;
    {   // issue first-tile loads (all rows provably in range)
        const ushort* ks = kP + (size_t)(kbase + kt_lo * KTW + krow) * 2304 + kcol;
        kr0 = *(const uint4*)ks; kr1 = *(const uint4*)(ks + 8);
        const ushort* vs = vP + (size_t)(kbase + kt_lo * KTW + vkey) * 2304 + vd0;
        vr0 = *(const uint4*)vs; vr1 = *(const uint4*)(vs + 8);
    }
    __syncthreads();
    // Q fragments -> registers (loop-invariant)
    s16x8 aq0 = *(const s16x8*)&Qs[(w * 16 + lm) * 72 + lg * 8];
    s16x8 aq1 = *(const s16x8*)&Qs[(w * 16 + lm) * 72 + lg * 8 + 32];
    // write first tile into buf0
    *(uint4*)&K0[krow * 72 + kcol]     = kr0;
    *(uint4*)&K0[krow * 72 + kcol + 8] = kr1;
    {
        union { uint4 u; ushort s[8]; } a, b;
        a.u = vr0; b.u = vr1;
        #pragma unroll
        for (int j = 0; j < 8; j++) V0[(vd0 + j) * 72 + vkey] = a.s[j];
        #pragma unroll
        for (int j = 0; j < 8; j++) V0[(vd0 + 8 + j) * 72 + vkey] = b.s[j];
    }
    __syncthreads();   // K0/V0 visible; all waves read aq -> K1 reusable

    float mq = -1e30f, lq = 0.f;     // per-query (lane lm) running state
    fx4 accO[4];
    #pragma unroll
    for (int rt = 0; rt < 4; rt++) accO[rt] = (fx4){0.f, 0.f, 0.f, 0.f};

    int q0 = qbase + w * 16;
    int qp = q0 + lm;
    const float scale = 0.125f;
    const fx4 zf = (fx4){0.f, 0.f, 0.f, 0.f};

    for (int kt = kt_lo; kt < kt_hi; kt++) {
        bool pre = (kt + 1 < kt_hi);
        if (pre) {   // issue next-tile loads (latency hides under compute)
            const ushort* ks = kP + (size_t)(kbase + (kt + 1) * KTW + krow) * 2304 + kcol;
            kr0 = *(const uint4*)ks; kr1 = *(const uint4*)(ks + 8);
            const ushort* vs = vP + (size_t)(kbase + (kt + 1) * KTW + vkey) * 2304 + vd0;
            vr0 = *(const uint4*)vs; vr1 = *(const uint4*)(vs + 8);
        }
        int cur = (kt - kt_lo) & 1;
        const ushort* Kc = cur ? K1 : K0;
        const ushort* Vc = cur ? V1 : V0;
        ushort* Kn = cur ? K0 : K1;
        ushort* Vn = cur ? V0 : V1;

        // swapped QK^T: D[key(lg*4+r within j*16 group)][query(lm)]
        fx4 sc[4];
        #pragma unroll
        for (int j = 0; j < 4; j++) {
            s16x8 ak0 = *(const s16x8*)&Kc[(j * 16 + lm) * 72 + lg * 8];
            s16x8 ak1 = *(const s16x8*)&Kc[(j * 16 + lm) * 72 + lg * 8 + 32];
            sc[j] = __builtin_amdgcn_mfma_f32_16x16x32_bf16(ak0, aq0, zf, 0, 0, 0);
            sc[j] = __builtin_amdgcn_mfma_f32_16x16x32_bf16(ak1, aq1, sc[j], 0, 0, 0);
        }
        // mask + scale + tile max (per-query, lane-local over 16 keys)
        float tmax = -1e30f;
        #pragma unroll
        for (int j = 0; j < 4; j++) {
            #pragma unroll
            for (int r = 0; r < 4; r++) {
                int krel = kt * KTW + j * 16 + lg * 4 + r;
                int dd = kbase + krel - qp;
                bool ok = (dd >= -WIN) && (dd <= WIN) && (Ms[krel] != 0.f);
                sc[j][r] = ok ? sc[j][r] * scale : -1e30f;
                tmax = fmaxf(tmax, sc[j][r]);
            }
        }
        tmax = fmaxf(tmax, __shfl_xor(tmax, 16, 64));
        tmax = fmaxf(tmax, __shfl_xor(tmax, 32, 64));

        // defer-max: rescale only when max grew beyond threshold
        bool grow = tmax > mq + 8.f;
        if (__any((int)grow)) {
            float nm = fmaxf(mq, tmax);
            float corr = __expf(mq - nm);
            mq = nm;
            lq *= corr;
            #pragma unroll
            for (int rt = 0; rt < 4; rt++) {
                accO[rt][0] *= corr; accO[rt][1] *= corr;
                accO[rt][2] *= corr; accO[rt][3] *= corr;
            }
        }
        // P = exp(S - mq); row sum; pack to bf16 and store [query][key]
        float rs = 0.f;
        #pragma unroll
        for (int j = 0; j < 4; j++) {
            float p0 = __expf(sc[j][0] - mq); if (sc[j][0] < -1e29f) p0 = 0.f;
            float p1 = __expf(sc[j][1] - mq); if (sc[j][1] < -1e29f) p1 = 0.f;
            float p2 = __expf(sc[j][2] - mq); if (sc[j][2] < -1e29f) p2 = 0.f;
            float p3 = __expf(sc[j][3] - mq); if (sc[j][3] < -1e29f) p3 = 0.f;
            rs += (p0 + p1) + (p2 + p3);
            uint lo = (uint)f2bf(p0) | ((uint)f2bf(p1) << 16);
            uint hi = (uint)f2bf(p2) | ((uint)f2bf(p3) << 16);
            *(uint2*)&Ps[(w * 16 + lm) * 72 + j * 16 + lg * 4] = make_uint2(lo, hi);
        }
        rs += __shfl_xor(rs, 16, 64);
        rs += __shfl_xor(rs, 32, 64);
        lq += rs;

        // PV: O^T[dim][query]
        s16x8 bp0 = *(const s16x8*)&Ps[(w * 16 + lm) * 72 + lg * 8];
        s16x8 bp1 = *(const s16x8*)&Ps[(w * 16 + lm) * 72 + lg * 8 + 32];
        #pragma unroll
        for (int rt = 0; rt < 4; rt++) {
            s16x8 av0 = *(const s16x8*)&Vc[(rt * 16 + lm) * 72 + lg * 8];
            s16x8 av1 = *(const s16x8*)&Vc[(rt * 16 + lm) * 72 + lg * 8 + 32];
            accO[rt] = __builtin_amdgcn_mfma_f32_16x16x32_bf16(av0, bp0, accO[rt], 0, 0, 0);
            accO[rt] = __builtin_amdgcn_mfma_f32_16x16x32_bf16(av1, bp1, accO[rt], 0, 0, 0);
        }

        if (pre) {   // write next tile into the other buffer, single barrier
            *(uint4*)&Kn[krow * 72 + kcol]     = kr0;
            *(uint4*)&Kn[krow * 72 + kcol + 8] = kr1;
            union { uint4 u; ushort s[8]; } a, b;
            a.u = vr0; b.u = vr1;
            #pragma unroll
            for (int j = 0; j < 8; j++) Vn[(vd0 + j) * 72 + vkey] = a.s[j];
            #pragma unroll
            for (int j = 0; j < 8; j++) Vn[(vd0 + 8 + j) * 72 + vkey] = b.s[j];
            __syncthreads();
        }
    }

    float inv = 1.f / lq;
    int q = q0 + lm;
    #pragma unroll
    for (int rt = 0; rt < 4; rt++) {
        int dbase = rt * 16 + lg * 4;
        uint2 wv;
        wv.x = (uint)f2bf(accO[rt][0] * inv) | ((uint)f2bf(accO[rt][1] * inv) << 16);
        wv.y = (uint)f2bf(accO[rt][2] * inv) | ((uint)f2bf(accO[rt][3] * inv) << 16);
        *(uint2*)(ctxb + (size_t)q * HID + h * 64 + dbase) = wv;
    }
}

// ---------------- fused heads: split-K partial GEMV (3 heads in one launch) ----------------
__global__ __launch_bounds__(256) void heads_partial_kernel(
    const float* __restrict__ x0,
    const float* __restrict__ W0, const float* __restrict__ W1, const float* __restrict__ W2,
    float* __restrict__ p0, float* __restrict__ p1, float* __restrict__ p2) {
    int which = blockIdx.z;
    const float* Wt = which == 0 ? W0 : which == 1 ? W1 : W2;
    float* part     = which == 0 ? p0 : which == 1 ? p1 : p2;
    int N           = which == 0 ? N_ICD : which == 1 ? N_CPT : N_CH;
    if (blockIdx.x * 64 >= N) return;
    __shared__ float red[256];
    int t = threadIdx.x;
    int nn = blockIdx.x * 64 + (t & 63);
    int ks = t >> 6;
    int kc = blockIdx.y;
    int h0 = kc * 96 + ks * 24;
    float s = 0.f;
    if (nn < N) {
        #pragma unroll
        for (int kk = 0; kk < 24; kk++)
            s += x0[h0 + kk] * Wt[(size_t)(h0 + kk) * N + nn];
    }
    red[t] = s;
    __syncthreads();
    if (t < 64 && nn < N)
        part[(size_t)kc * N + nn] = (red[t] + red[t + 64]) + (red[t + 128] + red[t + 192]);
}

// ---------------- fused combine+focal (33 blocks: 16 icd, 16 cpt, 1 ch) ----------------
__global__ __launch_bounds__(256) void heads_focal_kernel(
    const float* __restrict__ p0, const float* __restrict__ p1, const float* __restrict__ p2,
    const float* __restrict__ b0, const float* __restrict__ b1, const float* __restrict__ b2,
    const float* __restrict__ t0, const float* __restrict__ t1, const float* __restrict__ t2,
    float* __restrict__ lg0, float* __restrict__ lg1, float* __restrict__ lg2,
    float* __restrict__ fpart) {
    int b = blockIdx.x;
    int which = b < 16 ? 0 : (b < 32 ? 1 : 2);
    int bi = which == 0 ? b : (which == 1 ? b - 16 : 0);
    int nb = which == 2 ? 1 : 16;
    const float* part  = which == 0 ? p0 : which == 1 ? p1 : p2;
    const float* bias  = which == 0 ? b0 : which == 1 ? b1 : b2;
    const float* tgt   = which == 0 ? t0 : which == 1 ? t1 : t2;
    float* logits      = which == 0 ? lg0 : which == 1 ? lg1 : lg2;
    int N              = which == 0 ? N_ICD : which == 1 ? N_CPT : N_CH;
    __shared__ float red[256];
    int t = threadIdx.x;
    float s = 0.f;
    for (int i = bi * 256 + t; i < N; i += nb * 256) {
        float l = bias[i];
        #pragma unroll
        for (int kc = 0; kc < 8; kc++) l += part[(size_t)kc * N + i];
        logits[i] = l;
        float y = tgt[i];
        float bce = fmaxf(l, 0.f) - l * y + log1pf(expf(-fabsf(l)));
        float pt = expf(-bce);
        float om = 1.f - pt;
        s += om * om * bce;
    }
    red[t] = s;
    __syncthreads();
    for (int o = 128; o > 0; o >>= 1) {
        if (t < o) red[t] += red[t + o];
        __syncthreads();
    }
    if (t == 0) fpart[b] = red[0];
}

__global__ void final_loss_kernel(const float* __restrict__ parts, float* __restrict__ out) {
    if (threadIdx.x == 0 && blockIdx.x == 0) {
        float a = 0.f, b = 0.f, c;
        for (int i = 0; i < 16; i++) a += parts[i];
        for (int i = 0; i < 16; i++) b += parts[16 + i];
        c = parts[32];
        out[0] = a / (float)N_ICD + b / (float)N_CPT + c / (float)N_CH;
    }
}

// ---------------- launch ----------------
extern "C" void kernel_launch(void* const* d_in, const int* in_sizes, int n_in,
                              void* d_out, int out_size, void* d_ws, size_t ws_size,
                              hipStream_t stream) {
    const int*   ids      = (const int*)d_in[0];
    const float* mask     = (const float*)d_in[1];
    const float* icd_lab  = (const float*)d_in[2];
    const float* cpt_lab  = (const float*)d_in[3];
    const float* ch_lab   = (const float*)d_in[4];
    const float* we       = (const float*)d_in[5];
    const float* pe       = (const float*)d_in[6];
    const float* els      = (const float*)d_in[7];
    const float* elb      = (const float*)d_in[8];
    const float* Wq       = (const float*)d_in[9];
    const float* bq       = (const float*)d_in[10];
    const float* Wk       = (const float*)d_in[11];
    const float* bk       = (const float*)d_in[12];
    const float* Wv       = (const float*)d_in[13];
    const float* bv       = (const float*)d_in[14];
    const float* Wo       = (const float*)d_in[15];
    const float* bo       = (const float*)d_in[16];
    const float* l1s      = (const float*)d_in[17];
    const float* l1b      = (const float*)d_in[18];
    const float* Wi       = (const float*)d_in[19];
    const float* bi       = (const float*)d_in[20];
    const float* Wo2      = (const float*)d_in[21];
    const float* bo2      = (const float*)d_in[22];
    const float* l2s      = (const float*)d_in[23];
    const float* l2b      = (const float*)d_in[24];
    const float* W_icd    = (const float*)d_in[25];
    const float* b_icd    = (const float*)d_in[26];
    const float* W_cpt    = (const float*)d_in[27];
    const float* b_cpt    = (const float*)d_in[28];
    const float* W_ch     = (const float*)d_in[29];
    const float* b_ch     = (const float*)d_in[30];

    const size_t SH = (size_t)S_LEN * HID;
    const size_t WW = (size_t)HID * HID;
    const size_t WI = (size_t)HID * FF;

    char* base = (char*)d_ws;
    size_t off = 0;
    auto alloc = [&](size_t bytes) { void* p = base + off; off += (bytes + 255) & ~(size_t)255; return p; };

    float* x     = (float*)alloc(SH * 4);
    float* tmp   = (float*)alloc(SH * 4);
    float* bqkv  = (float*)alloc(2 * 2304 * 4);
    float* chl   = (float*)alloc(32 * 4);
    float* fpart = (float*)alloc(64 * 4);
    float* hp_icd = (float*)alloc((size_t)8 * N_ICD * 4);
    float* hp_cpt = (float*)alloc((size_t)8 * N_CPT * 4);
    float* hp_ch  = (float*)alloc((size_t)8 * 32 * 4);
    ushort* xb      = (ushort*)alloc(SH * 2);
    ushort* qkvb    = (ushort*)alloc((size_t)S_LEN * 2304 * 2);
    ushort* ctxb    = (ushort*)alloc(SH * 2);
    ushort* ffhb    = (ushort*)alloc((size_t)S_LEN * FF * 2);
    ushort* wt_qkvo = (ushort*)alloc((size_t)8 * WW * 2);
    ushort* wt_i    = (ushort*)alloc((size_t)2 * WI * 2);
    ushort* wt_o2   = (ushort*)alloc((size_t)2 * WI * 2);

    float* out = (float*)d_out;
    float* icd_logits = out + 1;
    float* cpt_logits = out + 1 + N_ICD;

    prep_kernel<<<dim3(96, 24, 13), 256, 0, stream>>>(
        Wq, Wk, Wv, Wo, Wi, Wo2, bq, bk, bv, wt_qkvo, wt_i, wt_o2, bqkv);

    embed_ln_kernel<<<S_LEN, 256, 0, stream>>>(ids, we, pe, els, elb, x, xb);

    for (int l = 0; l < NLAYER; l++) {
        const ushort* wt_qkv_l = wt_qkvo + (size_t)l * 4 * WW;
        const ushort* wt_o_l   = wt_qkvo + (size_t)l * 4 * WW + 3 * WW;
        const ushort* wt_i_l   = wt_i  + (size_t)l * WI;
        const ushort* wt_o2_l  = wt_o2 + (size_t)l * WI;

        gemm_mfma_kernel<128,0,0,1><<<dim3(2304/128, S_LEN/128), 256, 0, stream>>>(
            xb, wt_qkv_l, bqkv + l * 2304, nullptr, qkvb, S_LEN, 2304, HID);

        band_attn_kernel<<<dim3(S_LEN/QB, NHEAD), 256, 0, stream>>>(qkvb, mask, ctxb);

        gemm_mfma_kernel<64,0,1,0><<<dim3(HID/64, S_LEN/128), 256, 0, stream>>>(
            ctxb, wt_o_l, bo + l*HID, tmp, nullptr, S_LEN, HID, HID);
        residual_ln_kernel<<<S_LEN, 256, 0, stream>>>(x, tmp, l1s + l*HID, l1b + l*HID, xb);

        gemm_mfma_kernel<128,1,0,1><<<dim3(FF/128, S_LEN/128), 256, 0, stream>>>(
            xb, wt_i_l, bi + l*FF, nullptr, ffhb, S_LEN, FF, HID);
        gemm_mfma_kernel<64,0,1,0><<<dim3(HID/64, S_LEN/128), 256, 0, stream>>>(
            ffhb, wt_o2_l, bo2 + l*HID, tmp, nullptr, S_LEN, HID, FF);
        residual_ln_kernel<<<S_LEN, 256, 0, stream>>>(x, tmp, l2s + l*HID, l2b + l*HID, xb);
    }

    heads_partial_kernel<<<dim3((N_ICD + 63) / 64, 8, 3), 256, 0, stream>>>(
        x, W_icd, W_cpt, W_ch, hp_icd, hp_cpt, hp_ch);
    heads_focal_kernel<<<33, 256, 0, stream>>>(
        hp_icd, hp_cpt, hp_ch, b_icd, b_cpt, b_ch, icd_lab, cpt_lab, ch_lab,
        icd_logits, cpt_logits, chl, fpart);
    final_loss_kernel<<<1, 1, 0, stream>>>(fpart, out);
}